// Round 8
// baseline (18996.088 us; speedup 1.0000x reference)
//
#include <hip/hip_runtime.h>
#include <hip/hip_bf16.h>
#include <math.h>

#define NN 65536
#define MATD 131072L   // doubles per complex matrix (re plane + im plane)
#define MAT0 32768L    // header size in doubles

// ws header offsets (doubles)
#define SC_DT 0
#define SC_NUINV 3
#define SC_EXPM_S 4
#define SC_EXPM_SCALE 5
#define SC_NORMS2 6
#define SC_MU 7
// 8,9: n1,ninf of M ; 12,13: n1,ninf of S ; 14: F^2 of S
#define W_UNIT_RE 64
#define W_UNIT_IM 320
#define W_C_RE 576
#define W_C_IM 832
#define W_LD_RE 1088
#define W_LD_IM 1344
#define W_SU 1600
#define W_SLOT 1856
#define W_SLOTU 2112        // 256 entries -> ends 2368
#define W_W 2432            // 256*33*2 doubles -> ends 19328
#define BARB 19456          // barrier: page q at +q*512 (arrive line +0, gen line +16)
#define BARM 23552          // master line (own page)
#define TRBASE 24064        // 128 doubles per inversion (<=41 inversions used)
#define NRM_ROW 31872       // 256 row-sum partials
#define NRM_COL 32128       // 256 col-sum partials
#define NRM_DEV 32384       // 256 row sums of |M - I|  (ends 32640 < 32768)
#define NPOOL 256           // virtual pool capacity

// matrix slots
#define S_EW 0
#define S_NUW 1
#define S_LAT 2
#define S_T2 3
#define S_T3 4
#define S_T4 5
#define S_E1 6
#define S_E2 7
#define S_M 8
#define S_M2 9
#define S_Y 10
#define S_Y2 11
#define S_IY 12
#define S_X 13
#define S_X2 14
#define S_T 15
#define S_W 16
#define S_V 17
#define S_G 18
#define S_G2 19
#define PBASE 20            // S^k at PBASE+k-1, k=1..32 -> 20..51
#define POOL0 52            // physical pool

#define PI_D 3.14159265358979323846
#define LOG_SCALE 32.0      // 2 * 2^4 sqrt stages (2 DB + 2 NS-sqrt)

__device__ inline double ldin(const void* p, int i, int dt){
    if (dt == 0) return (double)__bfloat162float(((const __hip_bfloat16*)p)[i]);
    if (dt == 1) return (double)((const float*)p)[i];
    return ((const double*)p)[i];
}

// ---------------- init: zero header ----------------
__global__ __launch_bounds__(256) void k_init(double* ws){
    ws[blockIdx.x * 256 + threadIdx.x] = 0.0;   // grid 128 -> 32768
}

// ---------------- input dtype detection ----------------
__global__ __launch_bounds__(64) void k_detect(const void* x, double* ws){
    __shared__ int ok[3];
    int t = threadIdx.x;
    if (t < 3) ok[t] = 1;
    __syncthreads();
    const __hip_bfloat16* pb = (const __hip_bfloat16*)x;
    for (int k = t; k < 256; k += 64){
        float v = __bfloat162float(pb[k]);
        if (!(v > 0.40f && v < 1.60f)) ok[0] = 0;
    }
    const float* pf = (const float*)x;
    { float v = pf[t]; if (!(v > 0.40f && v < 1.60f)) ok[1] = 0; }
    const double* pd = (const double*)x;
    { double v = pd[t]; if (!(v > 0.40 && v < 1.60)) ok[2] = 0; }
    __syncthreads();
    if (t == 0) ws[SC_DT] = ok[0] ? 0.0 : (ok[1] ? 1.0 : 2.0);
}

// ---------------- small vector stage (1 block) ----------------
__global__ __launch_bounds__(256) void k_small(
    const void* xin, const void* Ar, const void* Ai,
    const void* cAr, const void* cAi,
    double* ws, float* out)
{
    __shared__ double xs[256], twc[256], tws[256], ur[256], ui[256], red[256];
    int t = threadIdx.x;
    int dt = (int)ws[SC_DT];
    double x = ldin(xin, t, dt);
    xs[t] = x;
    red[t] = log(x);
    double ang = -2.0 * PI_D * (double)t / 256.0;
    twc[t] = cos(ang); tws[t] = sin(ang);
    __syncthreads();
    for (int s = 128; s > 0; s >>= 1){ if (t < s) red[t] += red[t+s]; __syncthreads(); }
    double slog = red[0];
    __syncthreads();
    double dy = (t == 0) ? 0.0 : (x - xs[t-1]);
    double r = x * exp(-slog / 256.0);
    double unr = r * cos(dy), uni = r * sin(dy);
    ur[t] = unr; ui[t] = uni;
    ws[W_UNIT_RE + t] = unr; ws[W_UNIT_IM + t] = uni;
    __syncthreads();
    double fr = 0.0, fi = 0.0;
    for (int n = 0; n < 256; n++){
        int m = (t * n) & 255;
        double c = twc[m], s = tws[m];
        fr += ur[n]*c - ui[n]*s;
        fi += ur[n]*s + ui[n]*c;
    }
    red[t] = fr; __syncthreads();
    for (int s = 128; s > 0; s >>= 1){ if (t < s) red[t] += red[t+s]; __syncthreads(); }
    double sr = red[0]; __syncthreads();
    red[t] = fi; __syncthreads();
    for (int s = 128; s > 0; s >>= 1){ if (t < s) red[t] += red[t+s]; __syncthreads(); }
    double si = red[0];
    double den = sr*sr + si*si;
    double cr = (fr*sr + fi*si) / den, ci = (fi*sr - fr*si) / den;
    ws[W_C_RE + t] = cr; ws[W_C_IM + t] = ci;
    double ar = ldin(Ar, t, dt), ai = ldin(Ai, t, dt);
    double car = ldin(cAr, t, dt), cai = ldin(cAi, t, dt);
    double pr = ar*unr - ai*uni, pi = ar*uni + ai*unr;
    double qr = car*pr + cai*pi, qi = car*pi - cai*pr;
    out[t] = (float)(x + atan2(qi, qr));
    double ldr = 0.5 * log((qr*qr + qi*qi) / (unr*unr + uni*uni));
    double ldi = atan2(qi, qr) - atan2(uni, unr);
    ws[W_LD_RE + t] = ldr; ws[W_LD_IM + t] = ldi;
}

// ---------------- build Ew and new_uw (fp64 planes) ----------------
__global__ __launch_bounds__(256) void k_build_mats(
    const void* Ewr, const void* Ewi, const void* uwr, const void* uwi, double* ws)
{
    int ij = blockIdx.x * 256 + threadIdx.x;
    int i = ij >> 8, j = ij & 255;
    int dt = (int)ws[SC_DT];
    double* EW = ws + MAT0 + (size_t)S_EW * MATD;
    EW[ij] = ldin(Ewr, ij, dt); EW[NN + ij] = ldin(Ewi, ij, dt);
    double* U = ws + MAT0 + (size_t)S_NUW * MATD;
    if (i == 0){ U[ij] = ws[W_LD_RE + j]; U[NN + ij] = ws[W_LD_IM + j]; }
    else { int src = (i-1)*256 + j; U[ij] = ldin(uwr, src, dt); U[NN + ij] = ldin(uwi, src, dt); }
}

// ---------------- norms: ws[idx]=n1, ws[idx+1]=ninf ----
__global__ __launch_bounds__(256) void k_norm1inf(const double* M, double* ws, int idx)
{
    __shared__ double cs[256], rs[256];
    int t = threadIdx.x;
    double c = 0.0, r = 0.0;
    for (int i = 0; i < 256; i++){
        c += fabs(M[i*256 + t]) + fabs(M[NN + i*256 + t]);
        r += fabs(M[t*256 + i]) + fabs(M[NN + t*256 + i]);
    }
    cs[t] = c; rs[t] = r; __syncthreads();
    for (int s = 128; s > 0; s >>= 1){
        if (t < s){ cs[t] = fmax(cs[t], cs[t+s]); rs[t] = fmax(rs[t], rs[t+s]); }
        __syncthreads();
    }
    if (t == 0){
        ws[idx] = cs[0]; ws[idx+1] = rs[0];
        ws[SC_NUINV] = 1.0 / (cs[0] * rs[0]);
    }
}

// Frobenius^2 -> ws[14]
__global__ __launch_bounds__(256) void k_fro(const double* M, double* ws)
{
    __shared__ double red[256];
    int t = threadIdx.x;
    double s = 0.0;
    for (int i = 0; i < 256; i++){
        double a = M[i*256 + t], b = M[NN + i*256 + t];
        s += a*a + b*b;
    }
    red[t] = s; __syncthreads();
    for (int k = 128; k > 0; k >>= 1){ if (t < k) red[t] += red[t+k]; __syncthreads(); }
    if (t == 0) ws[14] = red[0];
}

// rigorous sigma_max upper bound: min( sqrt(n1*ninf), ||S||_F )
__global__ void k_snorm(double* ws)
{
    double b1 = sqrt(ws[12] * ws[13]);
    double b2 = sqrt(ws[14]);
    ws[SC_NORMS2] = fmin(b1, b2);
}

// ---------------- complex GEMM (host-launched; expm + powers path) ----------------
__global__ __launch_bounds__(256) void k_zgemm(
    const double* __restrict__ Ab, const double* __restrict__ Bb,
    double* __restrict__ Cb, const double* __restrict__ Db,
    int preA, int preB, double alpha, double beta, double gamma,
    double* __restrict__ ws, int fm, int round, int flagIdx, int trIdx,
    long sA, long sB, long sC)
{
    int z = blockIdx.z;
    const double* A = Ab + (size_t)z * sA;
    const double* B = Bb + (size_t)z * sB;
    double* C = Cb + (size_t)z * sC;
    int tx = threadIdx.x & 15, ty = threadIdx.x >> 4;
    int row = blockIdx.y * 16 + ty, col = blockIdx.x * 16 + tx;
    if (fm == 1 && round > (int)ws[SC_EXPM_S]){
        C[row*256 + col] = A[row*256 + col];
        C[NN + row*256 + col] = A[NN + row*256 + col];
        return;
    }
    __shared__ double Asr[16][17], Asi[16][17], Bsr[16][17], Bsi[16][17];
    double cr = 0.0, ci = 0.0;
    for (int k0 = 0; k0 < 256; k0 += 16){
        int ac = k0 + tx;
        double a_re = A[row*256 + ac], a_im = A[NN + row*256 + ac];
        if (preA == 1) a_im = -a_im;
        else if (preA == 2){ if (row == ac) a_re -= 1.0; }
        int br = k0 + ty;
        double b_re = B[br*256 + col], b_im = B[NN + br*256 + col];
        if (preB == 1){ b_re = ((br == col) ? 2.0 : 0.0) - b_re; b_im = -b_im; }
        Asr[ty][tx] = a_re; Asi[ty][tx] = a_im;
        Bsr[ty][tx] = b_re; Bsi[ty][tx] = b_im;
        __syncthreads();
        #pragma unroll
        for (int kk = 0; kk < 16; kk++){
            double xr = Asr[ty][kk], xi = Asi[ty][kk];
            double yr = Bsr[kk][tx], yi = Bsi[kk][tx];
            cr += xr*yr - xi*yi;
            ci += xr*yi + xi*yr;
        }
        __syncthreads();
    }
    double outr = alpha * cr, outi = alpha * ci;
    if (Db){ outr += beta * Db[row*256 + col]; outi += beta * Db[NN + row*256 + col]; }
    if (row == col) outr += gamma;
    C[row*256 + col] = outr;
    C[NN + row*256 + col] = outi;
}

// ---- elementwise combine (expm path) ----
__global__ __launch_bounds__(256) void k_combine(double* ws, int dst,
    int s1, int s2, int s3, int s4,
    double a1, double a2, double a3, double a4, double g, int mode)
{
    int ij = blockIdx.x * 256 + threadIdx.x;
    int i = ij >> 8, j = ij & 255;
    double f1 = 1.0, f2 = 1.0;
    if (mode == 1){ f1 = ws[SC_EXPM_SCALE]; }
    double* C = ws + MAT0 + (size_t)dst * MATD;
    double r = 0.0, m = 0.0;
    if (s1 >= 0){ const double* X = ws + MAT0 + (size_t)s1 * MATD; r += a1*f1*X[ij]; m += a1*f1*X[NN+ij]; }
    if (s2 >= 0){ const double* X = ws + MAT0 + (size_t)s2 * MATD; r += a2*f2*X[ij]; m += a2*f2*X[NN+ij]; }
    if (s3 >= 0){ const double* X = ws + MAT0 + (size_t)s3 * MATD; r += a3*X[ij]; m += a3*X[NN+ij]; }
    if (s4 >= 0){ const double* X = ws + MAT0 + (size_t)s4 * MATD; r += a4*X[ij]; m += a4*X[NN+ij]; }
    if (i == j) r += g;
    C[ij] = r; C[NN + ij] = m;
}

__global__ void k_expm_prep(double* ws)
{
    if (threadIdx.x == 0 && blockIdx.x == 0){
        double n1 = ws[8];
        int s = 0;
        if (n1 > 0.5){
            s = (int)ceil(log2(n1 / 0.5));
            if (s < 0) s = 0; if (s > 10) s = 10;
        }
        ws[SC_EXPM_S] = (double)s;
        ws[SC_EXPM_SCALE] = ldexp(1.0, -s);
    }
}

// ==================== cooperative logm machinery ====================
// 256 blocks x 512 threads. gemm2 runs two INDEPENDENT gemms concurrently
// (team0/team1, each full k-depth). NS inverse in R-X form, 1 barrier/iter,
// X0 never materialized for warm starts.
struct ShMemC {
    double Ar[2][16][17], Ai[2][16][17], Br[2][16][17], Bi[2][16][17];
    double redB[256];
    double trR[16], trI[16];
};

struct GOp {
    const double* A; const double* B; double* C;
    double sA, dA, sB, dB;        // operands: (sA*A + dA*I), (sB*B + dB*I)
    double alpha, beta;           // C = alpha*AB + beta*(sD*D + dD*I) + gamma*I
    const double* D; double sD, dD;
    double gamma;
    double* tr;                   // trace accumulator (only honored on op0)
};

struct Ctx {
    double* ws; ShMemC* sh;
    unsigned int bgen;
    int t, b, team, tt, tx, ty, bx, by, row, col, ij2, pl, li, lj, tr_idx;
    bool diagre;

    __device__ void init(double* ws_, ShMemC* sh_){
        ws = ws_; sh = sh_;
        t = threadIdx.x; b = blockIdx.x;
        team = t >> 8; tt = t & 255;
        tx = tt & 15; ty = tt >> 4;
        bx = b & 15; by = b >> 4;
        row = by*16 + ty; col = bx*16 + tx;
        ij2 = b*512 + t;
        pl = ij2 >> 16;
        int lin = ij2 & 65535;
        li = lin >> 8; lj = lin & 255;
        tr_idx = (lj << 8) + li + (pl ? NN : 0);
        diagre = (pl == 0) && (li == lj);
        bgen = __hip_atomic_load((unsigned int*)(ws + BARB + 16), __ATOMIC_RELAXED,
                                 __HIP_MEMORY_SCOPE_AGENT);
    }
    __device__ double* SL(int s){ return ws + MAT0 + (size_t)s * MATD; }

    // grid barrier: 8 arrive lines (4KB-page-spread, XCD-aligned groups) -> master
    __device__ void GS(){
        __syncthreads();
        if (t == 0){
            unsigned int g = bgen;
            int grp = b & 7;
            unsigned int* aline  = (unsigned int*)(ws + BARB + grp*512);
            unsigned int* gline  = (unsigned int*)(ws + BARB + grp*512 + 16);
            unsigned int* master = (unsigned int*)(ws + BARM);
            unsigned int a = __hip_atomic_fetch_add(aline, 1u, __ATOMIC_ACQ_REL,
                                                    __HIP_MEMORY_SCOPE_AGENT);
            if (a == 31u){
                unsigned int m = __hip_atomic_fetch_add(master, 1u, __ATOMIC_ACQ_REL,
                                                        __HIP_MEMORY_SCOPE_AGENT);
                if (m == 7u){
                    __hip_atomic_store(master, 0u, __ATOMIC_RELAXED, __HIP_MEMORY_SCOPE_AGENT);
                    for (int q = 0; q < 8; q++)
                        __hip_atomic_store((unsigned int*)(ws + BARB + q*512), 0u,
                                           __ATOMIC_RELAXED, __HIP_MEMORY_SCOPE_AGENT);
                    for (int q = 0; q < 8; q++)
                        __hip_atomic_store((unsigned int*)(ws + BARB + q*512 + 16), g + 1u,
                                           __ATOMIC_RELEASE, __HIP_MEMORY_SCOPE_AGENT);
                } else {
                    while (__hip_atomic_load(gline, __ATOMIC_ACQUIRE,
                                             __HIP_MEMORY_SCOPE_AGENT) == g)
                        __builtin_amdgcn_s_sleep(2);
                }
            } else {
                while (__hip_atomic_load(gline, __ATOMIC_ACQUIRE,
                                         __HIP_MEMORY_SCOPE_AGENT) == g)
                    __builtin_amdgcn_s_sleep(2);
            }
        }
        __syncthreads();
        bgen++;
    }

    // grid-uniform max over a 256-entry ws array (shfl + LDS)
    __device__ double bmax(int base){
        double v = ws[base + (t & 255)];
        #pragma unroll
        for (int m = 32; m >= 1; m >>= 1) v = fmax(v, __shfl_xor(v, m));
        if ((t & 63) == 0) sh->redB[t >> 6] = v;
        __syncthreads();
        double u = sh->redB[0];
        #pragma unroll
        for (int q = 1; q < 8; q++) u = fmax(u, sh->redB[q]);
        __syncthreads();
        return u;
    }

    // block b computes row-b and col-b abs sums (and optionally |M-I| row sum)
    __device__ void partials(const double* M, bool withDev){
        double v, dv = 0.0;
        if (t < 256){
            double e = M[b*256 + t], f2 = M[NN + b*256 + t];
            v = fabs(e) + fabs(f2);
            if (withDev) dv = fabs(e - ((b == t) ? 1.0 : 0.0)) + fabs(f2);
        } else {
            int c2 = t - 256;
            v = fabs(M[c2*256 + b]) + fabs(M[NN + c2*256 + b]);
        }
        #pragma unroll
        for (int m = 32; m >= 1; m >>= 1){ v += __shfl_xor(v, m); dv += __shfl_xor(dv, m); }
        if ((t & 63) == 0){ sh->redB[t >> 6] = v; sh->redB[8 + (t >> 6)] = dv; }
        __syncthreads();
        if (t == 0){
            ws[NRM_ROW + b] = sh->redB[0] + sh->redB[1] + sh->redB[2] + sh->redB[3];
            if (withDev)
                ws[NRM_DEV + b] = sh->redB[8] + sh->redB[9] + sh->redB[10] + sh->redB[11];
        }
        if (t == 256){
            ws[NRM_COL + b] = sh->redB[4] + sh->redB[5] + sh->redB[6] + sh->redB[7];
        }
        __syncthreads();
    }

    __device__ void ldAB(const double* A, const double* B, int s,
                         double sA, double dA, double sB, double dB,
                         double& ar_, double& ai_, double& br_, double& bi_){
        int kb = (team << 7) + (s << 4);
        int ac = kb + tx;
        ar_ = sA * A[row*256 + ac] + ((row == ac) ? dA : 0.0);
        ai_ = sA * A[NN + row*256 + ac];
        int brx = kb + ty;
        br_ = sB * B[brx*256 + col] + ((brx == col) ? dB : 0.0);
        bi_ = sB * B[NN + brx*256 + col];
    }

    // C = alpha*(sA*A+dA*I)(sB*B+dB*I) + beta*(sD*D+dD*I) + gamma*I ; split-k x2.
    __device__ void gemm(const double* A, const double* B, double* C,
                         double sA, double dA, double sB, double dB,
                         double alpha, double beta, const double* D,
                         double sD, double dD, double gamma, double* tr){
        double cr = 0.0, ci = 0.0;
        double par, pai, pbr, pbi;
        ldAB(A, B, 0, sA, dA, sB, dB, par, pai, pbr, pbi);
        for (int s = 0; s < 8; s++){
            sh->Ar[team][ty][tx] = par; sh->Ai[team][ty][tx] = pai;
            sh->Br[team][ty][tx] = pbr; sh->Bi[team][ty][tx] = pbi;
            __syncthreads();
            if (s < 7) ldAB(A, B, s+1, sA, dA, sB, dB, par, pai, pbr, pbi);
            #pragma unroll
            for (int kk = 0; kk < 16; kk++){
                double xr = sh->Ar[team][ty][kk], xi = sh->Ai[team][ty][kk];
                double yr = sh->Br[team][kk][tx], yi = sh->Bi[team][kk][tx];
                cr += xr*yr - xi*yi;
                ci += xr*yi + xi*yr;
            }
            __syncthreads();
        }
        if (team == 1){ sh->Ar[1][ty][tx] = cr; sh->Ai[1][ty][tx] = ci; }
        __syncthreads();
        if (team == 0){
            cr += sh->Ar[1][ty][tx]; ci += sh->Ai[1][ty][tx];
            cr *= alpha; ci *= alpha;
            if (D){
                cr += beta * (sD * D[row*256 + col] + ((row == col) ? dD : 0.0));
                ci += beta * (sD * D[NN + row*256 + col]);
            }
            if (row == col) cr += gamma;
            C[row*256 + col] = cr;
            C[NN + row*256 + col] = ci;
        }
        if (tr && bx == by){
            if (team == 0 && ty == tx){ sh->trR[ty] = cr; sh->trI[ty] = ci; }
            __syncthreads();
            if (t == 0){
                double sr = 0.0, si = 0.0;
                for (int q = 0; q < 16; q++){ sr += sh->trR[q]; si += sh->trI[q]; }
                atomicAdd(tr, sr); atomicAdd(tr + 1, si);
            }
        }
        __syncthreads();
    }

    // Two INDEPENDENT gemms concurrently: team0 runs o0, team1 runs o1,
    // each at full k-depth (same total FLOPs as two split-k gemms, but the
    // two memory streams overlap and no cross-team reduction is needed).
    // Trace honored on o0 only.
    __device__ void gemm2(const GOp& o0, const GOp& o1){
        const GOp& d = team ? o1 : o0;
        double cr = 0.0, ci = 0.0;
        double par, pai, pbr, pbi;
        {
            int ac = tx;
            par = d.sA * d.A[row*256 + ac] + ((row == ac) ? d.dA : 0.0);
            pai = d.sA * d.A[NN + row*256 + ac];
            int brx = ty;
            pbr = d.sB * d.B[brx*256 + col] + ((brx == col) ? d.dB : 0.0);
            pbi = d.sB * d.B[NN + brx*256 + col];
        }
        for (int s = 0; s < 16; s++){
            sh->Ar[team][ty][tx] = par; sh->Ai[team][ty][tx] = pai;
            sh->Br[team][ty][tx] = pbr; sh->Bi[team][ty][tx] = pbi;
            __syncthreads();
            if (s < 15){
                int kb = (s+1) << 4;
                int ac = kb + tx;
                par = d.sA * d.A[row*256 + ac] + ((row == ac) ? d.dA : 0.0);
                pai = d.sA * d.A[NN + row*256 + ac];
                int brx = kb + ty;
                pbr = d.sB * d.B[brx*256 + col] + ((brx == col) ? d.dB : 0.0);
                pbi = d.sB * d.B[NN + brx*256 + col];
            }
            #pragma unroll
            for (int kk = 0; kk < 16; kk++){
                double xr = sh->Ar[team][ty][kk], xi = sh->Ai[team][ty][kk];
                double yr = sh->Br[team][kk][tx], yi = sh->Bi[team][kk][tx];
                cr += xr*yr - xi*yi;
                ci += xr*yi + xi*yr;
            }
            __syncthreads();
        }
        cr *= d.alpha; ci *= d.alpha;
        if (d.D){
            cr += d.beta * (d.sD * d.D[row*256 + col] + ((row == col) ? d.dD : 0.0));
            ci += d.beta * (d.sD * d.D[NN + row*256 + col]);
        }
        if (row == col) cr += d.gamma;
        d.C[row*256 + col] = cr;
        d.C[NN + row*256 + col] = ci;
        if (o0.tr && bx == by){
            if (team == 0 && ty == tx){ sh->trR[ty] = cr; sh->trI[ty] = ci; }
            __syncthreads();
            if (t == 0){
                double sr = 0.0, si = 0.0;
                for (int q = 0; q < 16; q++){ sr += sh->trR[q]; si += sh->trI[q]; }
                atomicAdd(o0.tr, sr); atomicAdd(o0.tr + 1, si);
            }
        }
        __syncthreads();
    }

    // NS inverse of A in R-X form. Norm partials of A must be in NRM_* (synced).
    // mode 0: auto — warm (dev<0.95): X0 = 2I-A NEVER MATERIALIZED (synthesized
    //   in R0's B-operand and the first X-update); cold: scaled-Newton.
    // mode 2: seeded (caller pre-wrote S_X and grid-synced), cold fallback.
    // Exit: |tr(R)| < 1e-5.
    __device__ double* inv(const double* A, double dev, int maxit, int mode,
                           int invid, double& n1, double& ninf){
        double* X  = SL(S_X);  double* X2 = SL(S_X2);
        double* R  = SL(S_T);  double* R2 = SL(S_IY);
        n1 = bmax(NRM_COL); ninf = bmax(NRM_ROW);
        bool scaled = false; double a = 1e-7;
        bool virt = false;
        double* trb = ws + TRBASE + (size_t)invid * 128;   // pre-zeroed slots
        if (mode == 0){
            if (dev < 0.95){
                virt = true;   // R0 = I - A(2I - A), X0 synthesized
                gemm(A, A, R, 1,0, -1,2, -1.0, 0.0, nullptr, 0,0, 1.0, trb);
            } else {
                scaled = true;
                double al = 1.0 / (n1 * ninf);
                double v = A[tr_idx] * al;
                X[ij2] = pl ? -v : v;               // cold: X0 = conj(A)^T/(n1*ninf)
                GS();
                gemm(A, X, R, 1,0, 1,0, -1.0, 0.0, nullptr, 0,0, 1.0, trb);
            }
        } else {
            gemm(A, X, R, 1,0, 1,0, -1.0, 0.0, nullptr, 0,0, 1.0, trb);
        }
        GS();
        double* xc = X; double* xo = X2; double* rc = R; double* ro = R2;
        bool canFall = (mode == 2);
        for (int i = 0; i < maxit; i++){
            if (t == 0){ sh->trR[0] = trb[2*i]; sh->trI[0] = trb[2*i+1]; }
            __syncthreads();
            double resid = fabs(sh->trR[0]) + fabs(sh->trI[0]);
            __syncthreads();
            if (resid < 1e-5){
                if (virt){   // converged at X0 (rare): materialize it
                    double v = -A[ij2];
                    if (diagre) v += 2.0;
                    xc[ij2] = v;
                    GS();
                }
                break;
            }
            if (canFall && i >= 4 && resid > 1e4){
                // seeded start diverging -> rigorous cold restart
                canFall = false; scaled = true; a = 1e-7;
                double al = 1.0 / (n1 * ninf);
                double v = A[tr_idx] * al;
                xo[ij2] = pl ? -v : v;
                GS();
                gemm(A, xo, ro, 1,0, 1,0, -1.0, 0.0, nullptr, 0,0, 1.0, trb + 2*(i+1));
                GS();
                double* tm = xc; xc = xo; xo = tm;
                tm = rc; rc = ro; ro = tm;
                continue;
            }
            double xi_ = 1.0;
            if (scaled){
                if (a > 0.5) scaled = false;
                else { xi_ = 2.0/(1.0 + a); double o = 1.0 + a; a = 4.0*a/(o*o); }
            }
            double omx = 1.0 - xi_;
            // team0: R' = ((1-xi)I + xi R)^2 (+trace) ; team1: X' = xi^2 XR + xi(2-xi) X
            GOp oR = { rc, rc, ro, xi_, omx, xi_, omx, 1.0, 0.0, nullptr, 0,0, 0.0,
                       trb + 2*(i+1) };
            GOp oX;
            if (virt){
                // X0 = 2I - A synthesized in A-operand and D-term
                oX = GOp{ A, rc, xo, -1.0, 2.0, 1,0, xi_*xi_, xi_*(2.0 - xi_),
                          A, -1.0, 2.0, 0.0, nullptr };
                virt = false;
            } else {
                oX = GOp{ xc, rc, xo, 1,0, 1,0, xi_*xi_, xi_*(2.0 - xi_),
                          xc, 1.0, 0.0, 0.0, nullptr };
            }
            gemm2(oR, oX);
            GS();
            double* tm = xc; xc = xo; xo = tm;
            tm = rc; rc = ro; ro = tm;
        }
        return xc;
    }
};

// ---- probes: decompose per-phase cost (rocprof rows; dur/n = unit cost) ----
__global__ __launch_bounds__(512, 2) void k_probe_bar(double* __restrict__ ws, int n)
{
    __shared__ ShMemC sh;
    Ctx c; c.init(ws, &sh);
    for (int i = 0; i < n; i++) c.GS();
}

__global__ __launch_bounds__(512, 2) void k_probe_gemm(double* __restrict__ ws, int n)
{
    __shared__ ShMemC sh;
    Ctx c; c.init(ws, &sh);
    for (int i = 0; i < n; i++)
        c.gemm(c.SL(S_E1), c.SL(S_E2), c.SL(S_G2),
               1,0, 1,0, 1.0, 0.0, nullptr, 0,0, 0.0, nullptr);
}

// ---- stage: one scaled product-form DB sqrt pass: S_EW <- sqrt(S_EW) ----
__global__ __launch_bounds__(512, 2) void k_logm_db(double* __restrict__ ws, int invBase)
{
    __shared__ ShMemC sh;
    Ctx c; c.init(ws, &sh);
    double* dMm = c.SL(S_M);  double* dM2 = c.SL(S_M2);
    double* dYy = c.SL(S_Y);  double* dY2 = c.SL(S_Y2);
    double* dG  = c.SL(S_G);
    double* EW  = c.SL(S_EW);
    const int ij2 = c.ij2;

    dMm[ij2] = EW[ij2];
    dYy[ij2] = EW[ij2];
    c.partials(EW, true);
    c.GS();
    double* mc = dMm; double* mo = dM2; double* yc = dYy; double* yo = dY2;
    double dev = c.bmax(NRM_DEV);
    int invid = invBase;
    for (int it = 0; it < 20; it++){
        if (dev < 1e-7) break;
        double nm1, nminf;
        double* iy = c.inv(mc, dev, 40, 0, invid++, nm1, nminf);
        // phase: G = Y * M^-1  ||  norm partials of M^-1 (for mu)
        c.gemm(yc, iy, dG, 1,0, 1,0, 1.0, 0.0, nullptr, 0,0, 0.0, nullptr);
        c.partials(iy, false);
        c.GS();
        double ni1 = c.bmax(NRM_COL), niinf = c.bmax(NRM_ROW);
        double mu = pow((ni1 * niinf) / (nm1 * nminf), 0.125);
        if (!(mu > 0.125)) mu = 0.125;
        if (mu > 8.0) mu = 8.0;
        double mu2 = mu*mu, rmu = 1.0/mu, rmu2 = rmu*rmu;
        {   // M' = 0.25*(mu^2 M + mu^-2 M^-1) + 0.5 I ; Y' = 0.5*(mu Y + G/mu)
            double r = 0.25 * (mu2 * mc[ij2] + rmu2 * iy[ij2]);
            if (c.diagre) r += 0.5;
            mo[ij2] = r;
            yo[ij2] = 0.5 * (mu * yc[ij2] + rmu * dG[ij2]);
        }
        c.GS();
        c.partials(mo, true);
        c.GS();
        dev = c.bmax(NRM_DEV);
        double* tm = mc; mc = mo; mo = tm;
        tm = yc; yc = yo; yo = tm;
    }
    EW[ij2] = yc[ij2];                                     // result -> S_EW
}

// ---- stage: one inverse-free Newton-Schulz sqrt pass: S_EW <- sqrt(S_EW) ----
// input spectrum |arg| < pi/4 -> rho(I - B/c) < 1 for c = sqrt(n1*ninf).
__global__ __launch_bounds__(512, 2) void k_logm_sq(double* __restrict__ ws)
{
    __shared__ ShMemC sh;
    Ctx c; c.init(ws, &sh);
    double* dYy = c.SL(S_Y);  double* dY2 = c.SL(S_Y2);
    double* dX  = c.SL(S_X);  double* dX2 = c.SL(S_X2);
    double* dT  = c.SL(S_T);
    double* EW  = c.SL(S_EW);
    const int ij2 = c.ij2;

    c.partials(EW, false);
    c.GS();
    double cc = sqrt(c.bmax(NRM_COL) * c.bmax(NRM_ROW));
    double invc = 1.0 / cc, sc = sqrt(cc);
    dYy[ij2] = EW[ij2] * invc;                             // Y0 = B/c
    dX[ij2]  = c.diagre ? 1.0 : 0.0;                       // Z0 = I
    c.GS();
    double* Ycur = dYy; double* Yalt = dY2;
    double* Zcur = dX;  double* Zalt = dX2;
    for (int it = 0; it < 30; it++){
        c.gemm(Zcur, Ycur, dT, 1,0, 1,0, 1.0, 0.0, nullptr, 0,0, 0.0, nullptr); // E = Z Y
        c.GS();
        c.partials(dT, true);                              // ||E - I||inf
        c.GS();
        double dv = c.bmax(NRM_DEV);
        if (dv < 1e-11) break;
        // team0: Y' = 0.5 Y (3I - E) ; team1: Z' = 0.5 (3I - E) Z  (independent)
        GOp oY = { Ycur, dT, Yalt, 1,0, -1.0,3.0, 0.5, 0.0, nullptr, 0,0, 0.0, nullptr };
        GOp oZ = { dT, Zcur, Zalt, -1.0,3.0, 1,0, 0.5, 0.0, nullptr, 0,0, 0.0, nullptr };
        c.gemm2(oY, oZ);
        c.GS();
        double* tm = Ycur; Ycur = Yalt; Yalt = tm;
        tm = Zcur; Zcur = Zalt; Zalt = tm;
    }
    EW[ij2] = sc * Ycur[ij2];                              // result -> S_EW
}

// ---- stage: Cayley + adaptive artanh + S-build ----
__global__ __launch_bounds__(512, 2) void k_logm_cay(double* __restrict__ ws, int invBase)
{
    __shared__ ShMemC sh;
    Ctx c; c.init(ws, &sh);
    double* dX  = c.SL(S_X);
    double* dG  = c.SL(S_G);  double* dG2 = c.SL(S_G2);
    double* dW  = c.SL(S_W);  double* dV  = c.SL(S_V);
    double* dLT = c.SL(S_LAT);
    double* dS  = c.SL(PBASE);
    double* EW  = c.SL(S_EW);
    const int ij2 = c.ij2;

    // A = B + I ; seed X0 = 0.75I - 0.25B (resid = 0.25(I-B)^2, small)
    dG[ij2] = EW[ij2] + (c.diagre ? 1.0 : 0.0);
    dX[ij2] = -0.25 * EW[ij2] + (c.diagre ? 0.75 : 0.0);
    c.GS();
    c.partials(dG, false);
    c.GS();
    double cn1, cninf;
    double* giy = c.inv(dG, 0.0, 40, 2, invBase, cn1, cninf);
    c.gemm(EW, giy, dW, 1,-1, 1,0, 1.0, 0.0, nullptr, 0,0, 0.0, nullptr); // W=(B-I)(B+I)^-1
    c.GS();
    c.gemm(dW, dW, dV, 1,0, 1,0, 1.0, 0.0, nullptr, 0,0, 0.0, nullptr);   // V = W^2
    c.partials(dW, false);                                 // ||W||inf for degree
    c.GS();
    double nW = c.bmax(NRM_ROW);
    double q = nW * nW;
    int J = 19;
    if (q < 0.5){
        J = 1;
        double qp = q * q;
        while (J < 19 && qp >= 1e-16 * (1.0 - q)){ qp *= q; J++; }
    }
    dG[ij2] = c.diagre ? 1.0/(double)(2*J + 1) : 0.0;      // Horner seed
    c.GS();
    double* gc = dG; double* go = dG2;
    for (int j = J - 1; j >= 0; j--){
        c.gemm(dV, gc, go, 1,0, 1,0, 1.0, 0.0, nullptr, 0,0, 1.0/(double)(2*j + 1), nullptr);
        c.GS();
        double* tm = gc; gc = go; go = tm;
    }
    c.gemm(dW, gc, dLT, 1,0, 1,0, 1.0, 0.0, nullptr, 0,0, 0.0, nullptr);  // LAT = artanh(W)
    c.GS();
    double vv = dLT[ij2] - dLT[c.tr_idx];
    dS[ij2] = c.pl ? -LOG_SCALE * vv : LOG_SCALE * vv;     // S = 32*conj(LAT-LAT^T)
}

// theta per u (rigorous upper bound); theta>4 -> scaling+squaring pool
__global__ __launch_bounds__(256) void k_theta_pool(double* ws)
{
    __shared__ double th[256]; __shared__ int rk[256];
    int t = threadIdx.x;
    double nS = ws[SC_NORMS2];
    double cr = ws[W_C_RE + t], ci = ws[W_C_IM + t];
    th[t] = sqrt(cr*cr + ci*ci) * nS;
    __syncthreads();
    int r = 0;
    for (int v = 0; v < 256; v++){
        if (th[v] > th[t] || (th[v] == th[t] && v < t)) r++;
    }
    rk[t] = r;
    __syncthreads();
    if (t == 0){
        int cnt = 0;
        for (int u = 0; u < 256; u++){
            double s = 0.0; int slot = -1;
            if (th[u] > 4.0 && rk[u] < NPOOL){
                double e = ceil(log2(th[u] / 4.0));
                if (e < 1.0) e = 1.0; if (e > 12.0) e = 12.0;
                s = e; slot = cnt;
                ws[W_SLOTU + cnt] = (double)u;
                cnt++;
            }
            ws[W_SU + u] = s;
            ws[W_SLOT + u] = (double)slot;
        }
        for (int k = cnt; k < NPOOL; k++) ws[W_SLOTU + k] = -1.0;
    }
}

// weights w[u][k] = (c_u / 2^{s_u})^k / k!
__global__ __launch_bounds__(256) void k_weights(double* ws)
{
    int u = threadIdx.x;
    double sc = ldexp(1.0, -(int)ws[W_SU + u]);
    double cr = ws[W_C_RE + u] * sc, ci = ws[W_C_IM + u] * sc;
    double wr = 1.0, wi = 0.0;
    ws[W_W + (u*33)*2] = 1.0; ws[W_W + (u*33)*2 + 1] = 0.0;
    for (int k = 1; k <= 32; k++){
        double inv = 1.0 / (double)k;
        double nr = (wr*cr - wi*ci) * inv, ni = (wr*ci + wi*cr) * inv;
        wr = nr; wi = ni;
        ws[W_W + (u*33 + k)*2] = wr;
        ws[W_W + (u*33 + k)*2 + 1] = wi;
    }
}

// exp_tens[u] = sum_k w[u][k] S^k -> f32 out (non-pooled) or fp64 pool base
__global__ __launch_bounds__(256) void k_combo(double* ws, float* out, long off_ex, int f,
                                               int pass, int K)
{
    __shared__ double wre[16][33], wim[16][33];
    __shared__ int anywork;
    int t = threadIdx.x;
    int row = blockIdx.x, ug = blockIdx.y;
    if (t == 0) anywork = (pass == 0) ? 1 : 0;
    __syncthreads();
    if (pass > 0 && t < 16){
        int u = ug*16 + t;
        int slot = (int)ws[W_SLOT + u];
        int phys = slot - pass * K;
        if (slot >= 0 && phys >= 0 && phys < K) anywork = 1;
    }
    __syncthreads();
    if (!anywork) return;
    for (int i = t; i < 16*33; i += 256){
        int g = i / 33, k = i % 33;
        int u = ug*16 + g;
        wre[g][k] = ws[W_W + (u*33 + k)*2];
        wim[g][k] = ws[W_W + (u*33 + k)*2 + 1];
    }
    __syncthreads();
    int j = t, ij = row*256 + j;
    double ar[16], ai[16];
    #pragma unroll
    for (int g = 0; g < 16; g++){
        ar[g] = (row == j) ? wre[g][0] : 0.0;
        ai[g] = (row == j) ? wim[g][0] : 0.0;
    }
    for (int k = 1; k <= 32; k++){
        const double* SP = ws + MAT0 + (size_t)(PBASE + k - 1) * MATD;
        double sre = SP[ij], sim = SP[NN + ij];
        #pragma unroll
        for (int g = 0; g < 16; g++){
            ar[g] += wre[g][k]*sre - wim[g][k]*sim;
            ai[g] += wre[g][k]*sim + wim[g][k]*sre;
        }
    }
    for (int g = 0; g < 16; g++){
        int u = ug*16 + g;
        int slot = (int)ws[W_SLOT + u];
        if (slot >= 0){
            int phys = slot - pass * K;
            if (phys >= 0 && phys < K){
                double* P = ws + MAT0 + (size_t)(POOL0 + phys) * MATD;
                P[ij] = ar[g]; P[NN + ij] = ai[g];
            }
        } else if (pass == 0){
            long base = off_ex + (long)u * NN * f + (long)ij * f;
            out[base] = (float)ar[g];
            if (f == 2) out[base + 1] = (float)ai[g];
        }
    }
}

// pool squaring
__global__ __launch_bounds__(256) void k_pool_sq(double* ws, int round, int pass, int K)
{
    int z = blockIdx.z;
    int vs = pass * K + z;
    int u = (vs < NPOOL) ? (int)ws[W_SLOTU + vs] : -1;
    if (u < 0) return;
    if (round > (int)ws[W_SU + u]) return;
    const double* A = ws + MAT0 + (size_t)(POOL0 + ((round & 1) ? 0 : K) + z) * MATD;
    double* C = ws + MAT0 + (size_t)(POOL0 + ((round & 1) ? K : 0) + z) * MATD;
    int tx = threadIdx.x & 15, ty = threadIdx.x >> 4;
    int row = blockIdx.y*16 + ty, col = blockIdx.x*16 + tx;
    __shared__ double Asr[16][17], Asi[16][17], Bsr[16][17], Bsi[16][17];
    double cr = 0.0, ci = 0.0;
    for (int k0 = 0; k0 < 256; k0 += 16){
        Asr[ty][tx] = A[row*256 + k0 + tx];
        Asi[ty][tx] = A[NN + row*256 + k0 + tx];
        Bsr[ty][tx] = A[(k0 + ty)*256 + col];
        Bsi[ty][tx] = A[NN + (k0 + ty)*256 + col];
        __syncthreads();
        #pragma unroll
        for (int kk = 0; kk < 16; kk++){
            double xr = Asr[ty][kk], xi = Asi[ty][kk];
            double yr = Bsr[kk][tx], yi = Bsi[kk][tx];
            cr += xr*yr - xi*yi;
            ci += xr*yi + xi*yr;
        }
        __syncthreads();
    }
    C[row*256 + col] = cr;
    C[NN + row*256 + col] = ci;
}

__global__ __launch_bounds__(256) void k_pool_out(const double* ws, float* out, long off_ex,
                                                  int f, int pass, int K)
{
    int z = blockIdx.y;
    int vs = pass * K + z;
    int u = (vs < NPOOL) ? (int)ws[W_SLOTU + vs] : -1;
    if (u < 0) return;
    int su = (int)ws[W_SU + u];
    int ij = blockIdx.x * 256 + threadIdx.x;
    const double* P = ws + MAT0 + (size_t)(POOL0 + ((su & 1) ? K : 0) + z) * MATD;
    long base = off_ex + (long)u * NN * f + (long)ij * f;
    out[base] = (float)P[ij];
    if (f == 2) out[base + 1] = (float)P[NN + ij];
}

__global__ __launch_bounds__(256) void k_cast_out(const double* ws, int slot, float* out, long off, int f)
{
    int ij = blockIdx.x * 256 + threadIdx.x;
    const double* P = ws + MAT0 + (size_t)slot * MATD;
    out[off + (long)ij * f] = (float)P[ij];
    if (f == 2) out[off + (long)ij * f + 1] = (float)P[NN + ij];
}

// ============================ host ============================
extern "C" void kernel_launch(void* const* d_in, const int* in_sizes, int n_in,
                              void* d_out, int out_size, void* d_ws, size_t ws_size,
                              hipStream_t stream)
{
    double* ws = (double*)d_ws;
    float* out = (float*)d_out;

    int f = (out_size >= 33816832) ? 2 : 1;
    long off_ex = 256;
    long off_uw = off_ex + (long)f * 16777216L;
    long off_ew = off_uw + (long)f * 65536L;

    k_init<<<128, 256, 0, stream>>>(ws);
    k_detect<<<1, 64, 0, stream>>>(d_in[0], ws);
    k_small<<<1, 256, 0, stream>>>(d_in[0], d_in[1], d_in[2], d_in[3], d_in[4], ws, out);

    long slotsAvail = (long)(ws_size / 8 - MAT0) / MATD;
    if (slotsAvail < POOL0 + 32) return;
    int K = (int)((slotsAvail - POOL0) / 2);
    if (K > NPOOL) K = NPOOL;
    if (K < 16) K = 16;
    int P = (NPOOL + K - 1) / K;

    auto MP = [&](int s){ return ws + MAT0 + (size_t)s * MATD; };
    auto ZG = [&](int a, int b, int c, int preA, int preB, double al, double be,
                  int d, double ga, int fm, int round){
        k_zgemm<<<dim3(16,16,1), 256, 0, stream>>>(MP(a), MP(b), MP(c),
            d >= 0 ? MP(d) : nullptr, preA, preB, al, be, ga, ws,
            fm, round, 0, 0, 0L, 0L, 0L);
    };
    auto GEMM = [&](int a, int b, int c, int preA, int preB, double al, double be, int d, double ga){
        ZG(a, b, c, preA, preB, al, be, d, ga, 0, 0);
    };

    k_build_mats<<<256, 256, 0, stream>>>(d_in[5], d_in[6], d_in[7], d_in[8], ws);
    k_cast_out<<<256, 256, 0, stream>>>(ws, S_NUW, out, off_uw, f);

    // -------- expm(new_uw): scaling + Paterson-Stockmeyer deg-16 Taylor + squarings ----
    static const double INVF[17] = {
        1.0, 1.0, 0.5, 1.0/6.0, 1.0/24.0, 1.0/120.0, 1.0/720.0, 1.0/5040.0,
        1.0/40320.0, 1.0/362880.0, 1.0/3628800.0, 1.0/39916800.0, 1.0/479001600.0,
        1.0/6227020800.0, 1.0/87178291200.0, 1.0/1307674368000.0, 1.0/20922789888000.0 };
    k_norm1inf<<<1, 256, 0, stream>>>(MP(S_NUW), ws, 8);
    k_expm_prep<<<1, 64, 0, stream>>>(ws);
    k_combine<<<256, 256, 0, stream>>>(ws, S_LAT, S_NUW, -1, -1, -1, 1.0, 0, 0, 0, 0.0, 1);
    GEMM(S_LAT, S_LAT, S_T2, 0, 0, 1.0, 0.0, -1, 0.0);
    GEMM(S_T2, S_LAT, S_T3, 0, 0, 1.0, 0.0, -1, 0.0);
    GEMM(S_T2, S_T2, S_T4, 0, 0, 1.0, 0.0, -1, 0.0);
    k_combine<<<256, 256, 0, stream>>>(ws, S_E1, -1, -1, -1, -1, 0, 0, 0, 0, INVF[16], 0);
    for (int b = 3; b >= 0; b--){
        GEMM(S_T4, S_E1, S_E2, 0, 0, 1.0, 0.0, -1, 0.0);
        k_combine<<<256, 256, 0, stream>>>(ws, S_E1, S_E2, S_LAT, S_T2, S_T3,
            1.0, INVF[4*b+1], INVF[4*b+2], INVF[4*b+3], INVF[4*b], 0);
    }
    for (int r = 1; r <= 10; r++){
        int src = (r & 1) ? S_E1 : S_E2, dst = (r & 1) ? S_E2 : S_E1;
        ZG(src, src, dst, 0, 0, 1.0, 0.0, -1, 0.0, 1, r);
    }
    GEMM(S_EW, S_E1, S_M2, 1, 0, 1.0, 0.0, -1, 0.0);   // new_Ew = conj(Ew) expm(new_uw)
    k_cast_out<<<256, 256, 0, stream>>>(ws, S_M2, out, off_ew, f);

    // -------- probes: barrier cost and gemm wall as separate rocprof rows ----
    {
        int nb = 24, ng = 12;
        { void* a[] = { (void*)&ws, (void*)&nb };
          hipLaunchCooperativeKernel((void*)k_probe_bar, dim3(256), dim3(512), a, 0, stream); }
        { void* a[] = { (void*)&ws, (void*)&ng };
          hipLaunchCooperativeKernel((void*)k_probe_gemm, dim3(256), dim3(512), a, 0, stream); }
    }

    // -------- logm(Ew): 5 cooperative stage launches (rocprof per-stage rows) ----
    {
        int ib0 = 0, ib1 = 20, ib2 = 40;
        { void* a[] = { (void*)&ws, (void*)&ib0 };
          hipLaunchCooperativeKernel((void*)k_logm_db, dim3(256), dim3(512), a, 0, stream); }
        { void* a[] = { (void*)&ws, (void*)&ib1 };
          hipLaunchCooperativeKernel((void*)k_logm_db, dim3(256), dim3(512), a, 0, stream); }
        { void* a[] = { (void*)&ws };
          hipLaunchCooperativeKernel((void*)k_logm_sq, dim3(256), dim3(512), a, 0, stream); }
        { void* a[] = { (void*)&ws };
          hipLaunchCooperativeKernel((void*)k_logm_sq, dim3(256), dim3(512), a, 0, stream); }
        { void* a[] = { (void*)&ws, (void*)&ib2 };
          hipLaunchCooperativeKernel((void*)k_logm_cay, dim3(256), dim3(512), a, 0, stream); }
    }

    // -------- batched exp_tens = expm(c_u S): shared powers + pooled squaring --------
    k_norm1inf<<<1, 256, 0, stream>>>(MP(PBASE), ws, 12);
    k_fro<<<1, 256, 0, stream>>>(MP(PBASE), ws);
    k_snorm<<<1, 1, 0, stream>>>(ws);
    k_theta_pool<<<1, 256, 0, stream>>>(ws);
    k_weights<<<1, 256, 0, stream>>>(ws);
    for (int m = 1; m < 32; m *= 2){
        int cnt = (m < 32 - m) ? m : (32 - m);
        k_zgemm<<<dim3(16,16,cnt), 256, 0, stream>>>(MP(PBASE + m - 1), MP(PBASE), MP(PBASE + m),
            nullptr, 0, 0, 1.0, 0.0, 0.0, ws, 0, 0, 0, 0, 0L, MATD, MATD);
    }
    for (int p = 0; p < P; p++){
        k_combo<<<dim3(256,16), 256, 0, stream>>>(ws, out, off_ex, f, p, K);
        for (int r = 1; r <= 12; r++)
            k_pool_sq<<<dim3(16,16,K), 256, 0, stream>>>(ws, r, p, K);
        k_pool_out<<<dim3(256,K), 256, 0, stream>>>(ws, out, off_ex, f, p, K);
    }
}

// Round 9
// 11607.216 us; speedup vs baseline: 1.6366x; 1.6366x over previous
//
#include <hip/hip_runtime.h>
#include <hip/hip_bf16.h>
#include <math.h>

#define NN 65536
#define MATD 131072L   // doubles per complex matrix (re plane + im plane)
#define MAT0 32768L    // header size in doubles

// ws header offsets (doubles)
#define SC_DT 0
#define SC_NUINV 3
#define SC_EXPM_S 4
#define SC_EXPM_SCALE 5
#define SC_NORMS2 6
#define SC_MU 7
// 8,9: n1,ninf of M ; 12,13: n1,ninf of S ; 14: F^2 of S
#define W_UNIT_RE 64
#define W_UNIT_IM 320
#define W_C_RE 576
#define W_C_IM 832
#define W_LD_RE 1088
#define W_LD_IM 1344
#define W_SU 1600
#define W_SLOT 1856
#define W_SLOTU 2112        // 256 entries -> ends 2368
#define W_W 2432            // 256*33*2 doubles -> ends 19328
#define BARB 19456          // barrier: page q at +q*512 (arrive line +0, gen line +16)
#define BARM 23552          // master line (own page)
#define TRBASE 24064        // 128 doubles per inversion (<=41 inversions used)
#define NRM_ROW 31872       // 256 row-sum partials
#define NRM_COL 32128       // 256 col-sum partials
#define NRM_DEV 32384       // 256 row sums of |M - I|  (ends 32640 < 32768)
#define NPOOL 256           // virtual pool capacity

// matrix slots
#define S_EW 0
#define S_NUW 1
#define S_LAT 2
#define S_T2 3
#define S_T3 4
#define S_T4 5
#define S_E1 6
#define S_E2 7
#define S_M 8
#define S_M2 9
#define S_Y 10
#define S_Y2 11
#define S_IY 12
#define S_X 13
#define S_X2 14
#define S_T 15
#define S_W 16
#define S_V 17
#define S_G 18
#define S_G2 19
#define PBASE 20            // S^k at PBASE+k-1, k=1..32 -> 20..51
#define POOL0 52            // physical pool

#define PI_D 3.14159265358979323846
#define LOG_SCALE 32.0      // 2 * 2^4 sqrt stages (2 DB + 2 NS-sqrt)

__device__ inline double ldin(const void* p, int i, int dt){
    if (dt == 0) return (double)__bfloat162float(((const __hip_bfloat16*)p)[i]);
    if (dt == 1) return (double)((const float*)p)[i];
    return ((const double*)p)[i];
}

// ---------------- init: zero header ----------------
__global__ __launch_bounds__(256) void k_init(double* ws){
    ws[blockIdx.x * 256 + threadIdx.x] = 0.0;   // grid 128 -> 32768
}

// ---------------- input dtype detection ----------------
__global__ __launch_bounds__(64) void k_detect(const void* x, double* ws){
    __shared__ int ok[3];
    int t = threadIdx.x;
    if (t < 3) ok[t] = 1;
    __syncthreads();
    const __hip_bfloat16* pb = (const __hip_bfloat16*)x;
    for (int k = t; k < 256; k += 64){
        float v = __bfloat162float(pb[k]);
        if (!(v > 0.40f && v < 1.60f)) ok[0] = 0;
    }
    const float* pf = (const float*)x;
    { float v = pf[t]; if (!(v > 0.40f && v < 1.60f)) ok[1] = 0; }
    const double* pd = (const double*)x;
    { double v = pd[t]; if (!(v > 0.40 && v < 1.60)) ok[2] = 0; }
    __syncthreads();
    if (t == 0) ws[SC_DT] = ok[0] ? 0.0 : (ok[1] ? 1.0 : 2.0);
}

// ---------------- small vector stage (1 block) ----------------
__global__ __launch_bounds__(256) void k_small(
    const void* xin, const void* Ar, const void* Ai,
    const void* cAr, const void* cAi,
    double* ws, float* out)
{
    __shared__ double xs[256], twc[256], tws[256], ur[256], ui[256], red[256];
    int t = threadIdx.x;
    int dt = (int)ws[SC_DT];
    double x = ldin(xin, t, dt);
    xs[t] = x;
    red[t] = log(x);
    double ang = -2.0 * PI_D * (double)t / 256.0;
    twc[t] = cos(ang); tws[t] = sin(ang);
    __syncthreads();
    for (int s = 128; s > 0; s >>= 1){ if (t < s) red[t] += red[t+s]; __syncthreads(); }
    double slog = red[0];
    __syncthreads();
    double dy = (t == 0) ? 0.0 : (x - xs[t-1]);
    double r = x * exp(-slog / 256.0);
    double unr = r * cos(dy), uni = r * sin(dy);
    ur[t] = unr; ui[t] = uni;
    ws[W_UNIT_RE + t] = unr; ws[W_UNIT_IM + t] = uni;
    __syncthreads();
    double fr = 0.0, fi = 0.0;
    for (int n = 0; n < 256; n++){
        int m = (t * n) & 255;
        double c = twc[m], s = tws[m];
        fr += ur[n]*c - ui[n]*s;
        fi += ur[n]*s + ui[n]*c;
    }
    red[t] = fr; __syncthreads();
    for (int s = 128; s > 0; s >>= 1){ if (t < s) red[t] += red[t+s]; __syncthreads(); }
    double sr = red[0]; __syncthreads();
    red[t] = fi; __syncthreads();
    for (int s = 128; s > 0; s >>= 1){ if (t < s) red[t] += red[t+s]; __syncthreads(); }
    double si = red[0];
    double den = sr*sr + si*si;
    double cr = (fr*sr + fi*si) / den, ci = (fi*sr - fr*si) / den;
    ws[W_C_RE + t] = cr; ws[W_C_IM + t] = ci;
    double ar = ldin(Ar, t, dt), ai = ldin(Ai, t, dt);
    double car = ldin(cAr, t, dt), cai = ldin(cAi, t, dt);
    double pr = ar*unr - ai*uni, pi = ar*uni + ai*unr;
    double qr = car*pr + cai*pi, qi = car*pi - cai*pr;
    out[t] = (float)(x + atan2(qi, qr));
    double ldr = 0.5 * log((qr*qr + qi*qi) / (unr*unr + uni*uni));
    double ldi = atan2(qi, qr) - atan2(uni, unr);
    ws[W_LD_RE + t] = ldr; ws[W_LD_IM + t] = ldi;
}

// ---------------- build Ew and new_uw (fp64 planes) ----------------
__global__ __launch_bounds__(256) void k_build_mats(
    const void* Ewr, const void* Ewi, const void* uwr, const void* uwi, double* ws)
{
    int ij = blockIdx.x * 256 + threadIdx.x;
    int i = ij >> 8, j = ij & 255;
    int dt = (int)ws[SC_DT];
    double* EW = ws + MAT0 + (size_t)S_EW * MATD;
    EW[ij] = ldin(Ewr, ij, dt); EW[NN + ij] = ldin(Ewi, ij, dt);
    double* U = ws + MAT0 + (size_t)S_NUW * MATD;
    if (i == 0){ U[ij] = ws[W_LD_RE + j]; U[NN + ij] = ws[W_LD_IM + j]; }
    else { int src = (i-1)*256 + j; U[ij] = ldin(uwr, src, dt); U[NN + ij] = ldin(uwi, src, dt); }
}

// ---------------- norms: ws[idx]=n1, ws[idx+1]=ninf ----
__global__ __launch_bounds__(256) void k_norm1inf(const double* M, double* ws, int idx)
{
    __shared__ double cs[256], rs[256];
    int t = threadIdx.x;
    double c = 0.0, r = 0.0;
    for (int i = 0; i < 256; i++){
        c += fabs(M[i*256 + t]) + fabs(M[NN + i*256 + t]);
        r += fabs(M[t*256 + i]) + fabs(M[NN + t*256 + i]);
    }
    cs[t] = c; rs[t] = r; __syncthreads();
    for (int s = 128; s > 0; s >>= 1){
        if (t < s){ cs[t] = fmax(cs[t], cs[t+s]); rs[t] = fmax(rs[t], rs[t+s]); }
        __syncthreads();
    }
    if (t == 0){
        ws[idx] = cs[0]; ws[idx+1] = rs[0];
        ws[SC_NUINV] = 1.0 / (cs[0] * rs[0]);
    }
}

// Frobenius^2 -> ws[14]
__global__ __launch_bounds__(256) void k_fro(const double* M, double* ws)
{
    __shared__ double red[256];
    int t = threadIdx.x;
    double s = 0.0;
    for (int i = 0; i < 256; i++){
        double a = M[i*256 + t], b = M[NN + i*256 + t];
        s += a*a + b*b;
    }
    red[t] = s; __syncthreads();
    for (int k = 128; k > 0; k >>= 1){ if (t < k) red[t] += red[t+k]; __syncthreads(); }
    if (t == 0) ws[14] = red[0];
}

// rigorous sigma_max upper bound: min( sqrt(n1*ninf), ||S||_F )
__global__ void k_snorm(double* ws)
{
    double b1 = sqrt(ws[12] * ws[13]);
    double b2 = sqrt(ws[14]);
    ws[SC_NORMS2] = fmin(b1, b2);
}

// ---------------- complex GEMM (host-launched; expm + powers path) ----------------
__global__ __launch_bounds__(256) void k_zgemm(
    const double* __restrict__ Ab, const double* __restrict__ Bb,
    double* __restrict__ Cb, const double* __restrict__ Db,
    int preA, int preB, double alpha, double beta, double gamma,
    double* __restrict__ ws, int fm, int round, int flagIdx, int trIdx,
    long sA, long sB, long sC)
{
    int z = blockIdx.z;
    const double* A = Ab + (size_t)z * sA;
    const double* B = Bb + (size_t)z * sB;
    double* C = Cb + (size_t)z * sC;
    int tx = threadIdx.x & 15, ty = threadIdx.x >> 4;
    int row = blockIdx.y * 16 + ty, col = blockIdx.x * 16 + tx;
    if (fm == 1 && round > (int)ws[SC_EXPM_S]){
        C[row*256 + col] = A[row*256 + col];
        C[NN + row*256 + col] = A[NN + row*256 + col];
        return;
    }
    __shared__ double Asr[16][17], Asi[16][17], Bsr[16][17], Bsi[16][17];
    double cr = 0.0, ci = 0.0;
    for (int k0 = 0; k0 < 256; k0 += 16){
        int ac = k0 + tx;
        double a_re = A[row*256 + ac], a_im = A[NN + row*256 + ac];
        if (preA == 1) a_im = -a_im;
        else if (preA == 2){ if (row == ac) a_re -= 1.0; }
        int br = k0 + ty;
        double b_re = B[br*256 + col], b_im = B[NN + br*256 + col];
        if (preB == 1){ b_re = ((br == col) ? 2.0 : 0.0) - b_re; b_im = -b_im; }
        Asr[ty][tx] = a_re; Asi[ty][tx] = a_im;
        Bsr[ty][tx] = b_re; Bsi[ty][tx] = b_im;
        __syncthreads();
        #pragma unroll
        for (int kk = 0; kk < 16; kk++){
            double xr = Asr[ty][kk], xi = Asi[ty][kk];
            double yr = Bsr[kk][tx], yi = Bsi[kk][tx];
            cr += xr*yr - xi*yi;
            ci += xr*yi + xi*yr;
        }
        __syncthreads();
    }
    double outr = alpha * cr, outi = alpha * ci;
    if (Db){ outr += beta * Db[row*256 + col]; outi += beta * Db[NN + row*256 + col]; }
    if (row == col) outr += gamma;
    C[row*256 + col] = outr;
    C[NN + row*256 + col] = outi;
}

// ---- elementwise combine (expm path) ----
__global__ __launch_bounds__(256) void k_combine(double* ws, int dst,
    int s1, int s2, int s3, int s4,
    double a1, double a2, double a3, double a4, double g, int mode)
{
    int ij = blockIdx.x * 256 + threadIdx.x;
    int i = ij >> 8, j = ij & 255;
    double f1 = 1.0, f2 = 1.0;
    if (mode == 1){ f1 = ws[SC_EXPM_SCALE]; }
    double* C = ws + MAT0 + (size_t)dst * MATD;
    double r = 0.0, m = 0.0;
    if (s1 >= 0){ const double* X = ws + MAT0 + (size_t)s1 * MATD; r += a1*f1*X[ij]; m += a1*f1*X[NN+ij]; }
    if (s2 >= 0){ const double* X = ws + MAT0 + (size_t)s2 * MATD; r += a2*f2*X[ij]; m += a2*f2*X[NN+ij]; }
    if (s3 >= 0){ const double* X = ws + MAT0 + (size_t)s3 * MATD; r += a3*X[ij]; m += a3*X[NN+ij]; }
    if (s4 >= 0){ const double* X = ws + MAT0 + (size_t)s4 * MATD; r += a4*X[ij]; m += a4*X[NN+ij]; }
    if (i == j) r += g;
    C[ij] = r; C[NN + ij] = m;
}

__global__ void k_expm_prep(double* ws)
{
    if (threadIdx.x == 0 && blockIdx.x == 0){
        double n1 = ws[8];
        int s = 0;
        if (n1 > 0.5){
            s = (int)ceil(log2(n1 / 0.5));
            if (s < 0) s = 0; if (s > 10) s = 10;
        }
        ws[SC_EXPM_S] = (double)s;
        ws[SC_EXPM_SCALE] = ldexp(1.0, -s);
    }
}

// ==================== cooperative logm machinery ====================
// 256 blocks x 512 threads (1 block/CU). All gemm operand loads are issued in
// ONE register batch up-front (the lockstep-after-barrier congestion made the
// old 16 serial per-step round-trips the dominant per-phase cost). Relaxed
// spin + single acquire in the barrier avoids repeated L2 invalidates.
struct ShMemC {
    double Ar[2][16][17], Ai[2][16][17], Br[2][16][17], Bi[2][16][17];
    double redB[256];
    double trR[16], trI[16];
};

struct GOp {
    const double* A; const double* B; double* C;
    double sA, dA, sB, dB;        // operands: (sA*A + dA*I), (sB*B + dB*I)
    double alpha, beta;           // C = alpha*AB + beta*(sD*D + dD*I) + gamma*I
    const double* D; double sD, dD;
    double gamma;
    double* tr;                   // trace accumulator (only honored on op0)
};

struct Ctx {
    double* ws; ShMemC* sh;
    unsigned int bgen;
    int t, b, team, tt, tx, ty, bx, by, row, col, ij2, pl, li, lj, tr_idx;
    bool diagre;

    __device__ void init(double* ws_, ShMemC* sh_){
        ws = ws_; sh = sh_;
        t = threadIdx.x; b = blockIdx.x;
        team = t >> 8; tt = t & 255;
        tx = tt & 15; ty = tt >> 4;
        bx = b & 15; by = b >> 4;
        row = by*16 + ty; col = bx*16 + tx;
        ij2 = b*512 + t;
        pl = ij2 >> 16;
        int lin = ij2 & 65535;
        li = lin >> 8; lj = lin & 255;
        tr_idx = (lj << 8) + li + (pl ? NN : 0);
        diagre = (pl == 0) && (li == lj);
        bgen = __hip_atomic_load((unsigned int*)(ws + BARB + 16), __ATOMIC_RELAXED,
                                 __HIP_MEMORY_SCOPE_AGENT);
    }
    __device__ double* SL(int s){ return ws + MAT0 + (size_t)s * MATD; }

    __device__ void spinwait(unsigned int* gline, unsigned int g){
        while (__hip_atomic_load(gline, __ATOMIC_RELAXED,
                                 __HIP_MEMORY_SCOPE_AGENT) == g)
            __builtin_amdgcn_s_sleep(2);
        // single acquire to pair with the master's release (kept alive by use)
        if (__hip_atomic_load(gline, __ATOMIC_ACQUIRE,
                              __HIP_MEMORY_SCOPE_AGENT) == g)
            __builtin_amdgcn_s_sleep(1);
    }

    // grid barrier: 8 arrive lines (4KB-page-spread) -> master; gen broadcast
    __device__ void GS(){
        __syncthreads();
        if (t == 0){
            unsigned int g = bgen;
            int grp = b & 7;
            unsigned int* aline  = (unsigned int*)(ws + BARB + grp*512);
            unsigned int* gline  = (unsigned int*)(ws + BARB + grp*512 + 16);
            unsigned int* master = (unsigned int*)(ws + BARM);
            unsigned int a = __hip_atomic_fetch_add(aline, 1u, __ATOMIC_ACQ_REL,
                                                    __HIP_MEMORY_SCOPE_AGENT);
            if (a == 31u){
                unsigned int m = __hip_atomic_fetch_add(master, 1u, __ATOMIC_ACQ_REL,
                                                        __HIP_MEMORY_SCOPE_AGENT);
                if (m == 7u){
                    __hip_atomic_store(master, 0u, __ATOMIC_RELAXED, __HIP_MEMORY_SCOPE_AGENT);
                    for (int q = 0; q < 8; q++)
                        __hip_atomic_store((unsigned int*)(ws + BARB + q*512), 0u,
                                           __ATOMIC_RELAXED, __HIP_MEMORY_SCOPE_AGENT);
                    for (int q = 0; q < 8; q++)
                        __hip_atomic_store((unsigned int*)(ws + BARB + q*512 + 16), g + 1u,
                                           __ATOMIC_RELEASE, __HIP_MEMORY_SCOPE_AGENT);
                } else spinwait(gline, g);
            } else spinwait(gline, g);
        }
        __syncthreads();
        bgen++;
    }

    // grid-uniform max over a 256-entry ws array (shfl + LDS)
    __device__ double bmax(int base){
        double v = ws[base + (t & 255)];
        #pragma unroll
        for (int m = 32; m >= 1; m >>= 1) v = fmax(v, __shfl_xor(v, m));
        if ((t & 63) == 0) sh->redB[t >> 6] = v;
        __syncthreads();
        double u = sh->redB[0];
        #pragma unroll
        for (int q = 1; q < 8; q++) u = fmax(u, sh->redB[q]);
        __syncthreads();
        return u;
    }

    // block b computes row-b and col-b abs sums (and optionally |M-I| row sum)
    __device__ void partials(const double* M, bool withDev){
        double v, dv = 0.0;
        if (t < 256){
            double e = M[b*256 + t], f2 = M[NN + b*256 + t];
            v = fabs(e) + fabs(f2);
            if (withDev) dv = fabs(e - ((b == t) ? 1.0 : 0.0)) + fabs(f2);
        } else {
            int c2 = t - 256;
            v = fabs(M[c2*256 + b]) + fabs(M[NN + c2*256 + b]);
        }
        #pragma unroll
        for (int m = 32; m >= 1; m >>= 1){ v += __shfl_xor(v, m); dv += __shfl_xor(dv, m); }
        if ((t & 63) == 0){ sh->redB[t >> 6] = v; sh->redB[8 + (t >> 6)] = dv; }
        __syncthreads();
        if (t == 0){
            ws[NRM_ROW + b] = sh->redB[0] + sh->redB[1] + sh->redB[2] + sh->redB[3];
            if (withDev)
                ws[NRM_DEV + b] = sh->redB[8] + sh->redB[9] + sh->redB[10] + sh->redB[11];
        }
        if (t == 256){
            ws[NRM_COL + b] = sh->redB[4] + sh->redB[5] + sh->redB[6] + sh->redB[7];
        }
        __syncthreads();
    }

    // C = alpha*(sA*A+dA*I)(sB*B+dB*I) + beta*(sD*D+dD*I) + gamma*I.
    // split-k x2 across teams; ALL 8 k-steps' operands loaded in one burst.
    __device__ void gemm(const double* A, const double* B, double* C,
                         double sA, double dA, double sB, double dB,
                         double alpha, double beta, const double* D,
                         double sD, double dD, double gamma, double* tr){
        double lar[8], lai[8], lbr[8], lbi[8];
        const double* Arow = A + (size_t)row*256;
        const double* Bcol = B + col;
        #pragma unroll
        for (int s = 0; s < 8; s++){
            int kb = (team << 7) + (s << 4);
            lar[s] = Arow[kb + tx];
            lai[s] = Arow[NN + kb + tx];
            lbr[s] = Bcol[(size_t)(kb + ty)*256];
            lbi[s] = Bcol[(size_t)NN + (size_t)(kb + ty)*256];
        }
        {   // pin the burst: force all loads complete before compute begins
            double dm = 0.0;
            #pragma unroll
            for (int s = 0; s < 8; s++) dm += lar[s] + lai[s] + lbr[s] + lbi[s];
            asm volatile("" :: "v"(dm));
        }
        double cr = 0.0, ci = 0.0;
        #pragma unroll
        for (int s = 0; s < 8; s++){
            int kb = (team << 7) + (s << 4);
            int ac = kb + tx, brx = kb + ty;
            sh->Ar[team][ty][tx] = sA * lar[s] + ((row == ac) ? dA : 0.0);
            sh->Ai[team][ty][tx] = sA * lai[s];
            sh->Br[team][ty][tx] = sB * lbr[s] + ((brx == col) ? dB : 0.0);
            sh->Bi[team][ty][tx] = sB * lbi[s];
            __syncthreads();
            #pragma unroll
            for (int kk = 0; kk < 16; kk++){
                double xr = sh->Ar[team][ty][kk], xi = sh->Ai[team][ty][kk];
                double yr = sh->Br[team][kk][tx], yi = sh->Bi[team][kk][tx];
                cr += xr*yr - xi*yi;
                ci += xr*yi + xi*yr;
            }
            __syncthreads();
        }
        if (team == 1){ sh->Ar[1][ty][tx] = cr; sh->Ai[1][ty][tx] = ci; }
        __syncthreads();
        if (team == 0){
            cr += sh->Ar[1][ty][tx]; ci += sh->Ai[1][ty][tx];
            cr *= alpha; ci *= alpha;
            if (D){
                cr += beta * (sD * D[row*256 + col] + ((row == col) ? dD : 0.0));
                ci += beta * (sD * D[NN + row*256 + col]);
            }
            if (row == col) cr += gamma;
            C[row*256 + col] = cr;
            C[NN + row*256 + col] = ci;
        }
        if (tr && bx == by){
            if (team == 0 && ty == tx){ sh->trR[ty] = cr; sh->trI[ty] = ci; }
            __syncthreads();
            if (t == 0){
                double sr = 0.0, si = 0.0;
                for (int q = 0; q < 16; q++){ sr += sh->trR[q]; si += sh->trI[q]; }
                atomicAdd(tr, sr); atomicAdd(tr + 1, si);
            }
        }
        __syncthreads();
    }

    // Two INDEPENDENT gemms concurrently (team0 -> o0, team1 -> o1), each at
    // full k-depth; ALL 16 k-steps' operands loaded in one burst.
    __device__ void gemm2(const GOp& o0, const GOp& o1){
        const GOp& d = team ? o1 : o0;
        double lar[16], lai[16], lbr[16], lbi[16];
        const double* Arow = d.A + (size_t)row*256;
        const double* Bcol = d.B + col;
        #pragma unroll
        for (int s = 0; s < 16; s++){
            int kb = s << 4;
            lar[s] = Arow[kb + tx];
            lai[s] = Arow[NN + kb + tx];
            lbr[s] = Bcol[(size_t)(kb + ty)*256];
            lbi[s] = Bcol[(size_t)NN + (size_t)(kb + ty)*256];
        }
        {
            double dm = 0.0;
            #pragma unroll
            for (int s = 0; s < 16; s++) dm += lar[s] + lai[s] + lbr[s] + lbi[s];
            asm volatile("" :: "v"(dm));
        }
        double cr = 0.0, ci = 0.0;
        #pragma unroll
        for (int s = 0; s < 16; s++){
            int kb = s << 4;
            int ac = kb + tx, brx = kb + ty;
            sh->Ar[team][ty][tx] = d.sA * lar[s] + ((row == ac) ? d.dA : 0.0);
            sh->Ai[team][ty][tx] = d.sA * lai[s];
            sh->Br[team][ty][tx] = d.sB * lbr[s] + ((brx == col) ? d.dB : 0.0);
            sh->Bi[team][ty][tx] = d.sB * lbi[s];
            __syncthreads();
            #pragma unroll
            for (int kk = 0; kk < 16; kk++){
                double xr = sh->Ar[team][ty][kk], xi = sh->Ai[team][ty][kk];
                double yr = sh->Br[team][kk][tx], yi = sh->Bi[team][kk][tx];
                cr += xr*yr - xi*yi;
                ci += xr*yi + xi*yr;
            }
            __syncthreads();
        }
        cr *= d.alpha; ci *= d.alpha;
        if (d.D){
            cr += d.beta * (d.sD * d.D[row*256 + col] + ((row == col) ? d.dD : 0.0));
            ci += d.beta * (d.sD * d.D[NN + row*256 + col]);
        }
        if (row == col) cr += d.gamma;
        d.C[row*256 + col] = cr;
        d.C[NN + row*256 + col] = ci;
        if (o0.tr && bx == by){
            if (team == 0 && ty == tx){ sh->trR[ty] = cr; sh->trI[ty] = ci; }
            __syncthreads();
            if (t == 0){
                double sr = 0.0, si = 0.0;
                for (int q = 0; q < 16; q++){ sr += sh->trR[q]; si += sh->trI[q]; }
                atomicAdd(o0.tr, sr); atomicAdd(o0.tr + 1, si);
            }
        }
        __syncthreads();
    }

    // NS inverse of A in R-X form. Norm partials of A must be in NRM_* (synced).
    // mode 0: auto — warm (dev<0.95): X0 = 2I-A synthesized (never materialized);
    //   cold: optimally-scaled Newton (cond/4 per iter).
    // mode 2: seeded (caller pre-wrote S_X and grid-synced), cold fallback.
    // Exit: |tr(R)| < 1e-5.
    __device__ double* inv(const double* A, double dev, int maxit, int mode,
                           int invid, double& n1, double& ninf){
        double* X  = SL(S_X);  double* X2 = SL(S_X2);
        double* R  = SL(S_T);  double* R2 = SL(S_IY);
        n1 = bmax(NRM_COL); ninf = bmax(NRM_ROW);
        bool scaled = false; double a = 1e-7;
        bool virt = false;
        double* trb = ws + TRBASE + (size_t)invid * 128;   // pre-zeroed slots
        if (mode == 0){
            if (dev < 0.95){
                virt = true;   // R0 = I - A(2I - A), X0 synthesized
                gemm(A, A, R, 1,0, -1,2, -1.0, 0.0, nullptr, 0,0, 1.0, trb);
            } else {
                scaled = true;
                double al = 1.0 / (n1 * ninf);
                double v = A[tr_idx] * al;
                X[ij2] = pl ? -v : v;               // cold: X0 = conj(A)^T/(n1*ninf)
                GS();
                gemm(A, X, R, 1,0, 1,0, -1.0, 0.0, nullptr, 0,0, 1.0, trb);
            }
        } else {
            gemm(A, X, R, 1,0, 1,0, -1.0, 0.0, nullptr, 0,0, 1.0, trb);
        }
        GS();
        double* xc = X; double* xo = X2; double* rc = R; double* ro = R2;
        bool canFall = (mode == 2);
        for (int i = 0; i < maxit; i++){
            if (t == 0){ sh->trR[0] = trb[2*i]; sh->trI[0] = trb[2*i+1]; }
            __syncthreads();
            double resid = fabs(sh->trR[0]) + fabs(sh->trI[0]);
            __syncthreads();
            if (resid < 1e-5){
                if (virt){   // converged at X0 (rare): materialize it
                    double v = -A[ij2];
                    if (diagre) v += 2.0;
                    xc[ij2] = v;
                    GS();
                }
                break;
            }
            if (canFall && i >= 4 && resid > 1e4){
                // seeded start diverging -> rigorous cold restart
                canFall = false; scaled = true; a = 1e-7;
                double al = 1.0 / (n1 * ninf);
                double v = A[tr_idx] * al;
                xo[ij2] = pl ? -v : v;
                GS();
                gemm(A, xo, ro, 1,0, 1,0, -1.0, 0.0, nullptr, 0,0, 1.0, trb + 2*(i+1));
                GS();
                double* tm = xc; xc = xo; xo = tm;
                tm = rc; rc = ro; ro = tm;
                continue;
            }
            double xi_ = 1.0;
            if (scaled){
                if (a > 0.5) scaled = false;
                else { xi_ = 2.0/(1.0 + a); double o = 1.0 + a; a = 4.0*a/(o*o); }
            }
            double omx = 1.0 - xi_;
            // team0: R' = ((1-xi)I + xi R)^2 (+trace) ; team1: X' = xi^2 XR + xi(2-xi) X
            GOp oR = { rc, rc, ro, xi_, omx, xi_, omx, 1.0, 0.0, nullptr, 0,0, 0.0,
                       trb + 2*(i+1) };
            GOp oX;
            if (virt){
                oX = GOp{ A, rc, xo, -1.0, 2.0, 1,0, xi_*xi_, xi_*(2.0 - xi_),
                          A, -1.0, 2.0, 0.0, nullptr };
                virt = false;
            } else {
                oX = GOp{ xc, rc, xo, 1,0, 1,0, xi_*xi_, xi_*(2.0 - xi_),
                          xc, 1.0, 0.0, 0.0, nullptr };
            }
            gemm2(oR, oX);
            GS();
            double* tm = xc; xc = xo; xo = tm;
            tm = rc; rc = ro; ro = tm;
        }
        return xc;
    }
};

// ---- stage: one scaled product-form DB sqrt pass: S_EW <- sqrt(S_EW) ----
__global__ __launch_bounds__(512, 1) void k_logm_db(double* __restrict__ ws, int invBase)
{
    __shared__ ShMemC sh;
    Ctx c; c.init(ws, &sh);
    double* dMm = c.SL(S_M);  double* dM2 = c.SL(S_M2);
    double* dYy = c.SL(S_Y);  double* dY2 = c.SL(S_Y2);
    double* dG  = c.SL(S_G);
    double* EW  = c.SL(S_EW);
    const int ij2 = c.ij2;

    dMm[ij2] = EW[ij2];
    dYy[ij2] = EW[ij2];
    c.partials(EW, true);
    c.GS();
    double* mc = dMm; double* mo = dM2; double* yc = dYy; double* yo = dY2;
    double dev = c.bmax(NRM_DEV);
    int invid = invBase;
    for (int it = 0; it < 20; it++){
        if (dev < 1e-7) break;
        double nm1, nminf;
        double* iy = c.inv(mc, dev, 40, 0, invid++, nm1, nminf);
        // phase: G = Y * M^-1  ||  norm partials of M^-1 (for mu)
        c.gemm(yc, iy, dG, 1,0, 1,0, 1.0, 0.0, nullptr, 0,0, 0.0, nullptr);
        c.partials(iy, false);
        c.GS();
        double ni1 = c.bmax(NRM_COL), niinf = c.bmax(NRM_ROW);
        double mu = pow((ni1 * niinf) / (nm1 * nminf), 0.125);
        if (!(mu > 0.125)) mu = 0.125;
        if (mu > 8.0) mu = 8.0;
        double mu2 = mu*mu, rmu = 1.0/mu, rmu2 = rmu*rmu;
        {   // M' = 0.25*(mu^2 M + mu^-2 M^-1) + 0.5 I ; Y' = 0.5*(mu Y + G/mu)
            double r = 0.25 * (mu2 * mc[ij2] + rmu2 * iy[ij2]);
            if (c.diagre) r += 0.5;
            mo[ij2] = r;
            yo[ij2] = 0.5 * (mu * yc[ij2] + rmu * dG[ij2]);
        }
        c.GS();
        c.partials(mo, true);
        c.GS();
        dev = c.bmax(NRM_DEV);
        double* tm = mc; mc = mo; mo = tm;
        tm = yc; yc = yo; yo = tm;
    }
    EW[ij2] = yc[ij2];                                     // result -> S_EW
}

// ---- stage: one inverse-free Newton-Schulz sqrt pass: S_EW <- sqrt(S_EW) ----
// input spectrum |arg| < pi/4 -> rho(I - B/c) < 1 for c = sqrt(n1*ninf).
__global__ __launch_bounds__(512, 1) void k_logm_sq(double* __restrict__ ws)
{
    __shared__ ShMemC sh;
    Ctx c; c.init(ws, &sh);
    double* dYy = c.SL(S_Y);  double* dY2 = c.SL(S_Y2);
    double* dX  = c.SL(S_X);  double* dX2 = c.SL(S_X2);
    double* dT  = c.SL(S_T);
    double* EW  = c.SL(S_EW);
    const int ij2 = c.ij2;

    c.partials(EW, false);
    c.GS();
    double cc = sqrt(c.bmax(NRM_COL) * c.bmax(NRM_ROW));
    double invc = 1.0 / cc, sc = sqrt(cc);
    dYy[ij2] = EW[ij2] * invc;                             // Y0 = B/c
    dX[ij2]  = c.diagre ? 1.0 : 0.0;                       // Z0 = I
    c.GS();
    double* Ycur = dYy; double* Yalt = dY2;
    double* Zcur = dX;  double* Zalt = dX2;
    for (int it = 0; it < 30; it++){
        c.gemm(Zcur, Ycur, dT, 1,0, 1,0, 1.0, 0.0, nullptr, 0,0, 0.0, nullptr); // E = Z Y
        c.GS();
        c.partials(dT, true);                              // ||E - I||inf
        c.GS();
        double dv = c.bmax(NRM_DEV);
        if (dv < 1e-11) break;
        // team0: Y' = 0.5 Y (3I - E) ; team1: Z' = 0.5 (3I - E) Z  (independent)
        GOp oY = { Ycur, dT, Yalt, 1,0, -1.0,3.0, 0.5, 0.0, nullptr, 0,0, 0.0, nullptr };
        GOp oZ = { dT, Zcur, Zalt, -1.0,3.0, 1,0, 0.5, 0.0, nullptr, 0,0, 0.0, nullptr };
        c.gemm2(oY, oZ);
        c.GS();
        double* tm = Ycur; Ycur = Yalt; Yalt = tm;
        tm = Zcur; Zcur = Zalt; Zalt = tm;
    }
    EW[ij2] = sc * Ycur[ij2];                              // result -> S_EW
}

// ---- stage: Cayley + adaptive artanh + S-build ----
__global__ __launch_bounds__(512, 1) void k_logm_cay(double* __restrict__ ws, int invBase)
{
    __shared__ ShMemC sh;
    Ctx c; c.init(ws, &sh);
    double* dX  = c.SL(S_X);
    double* dG  = c.SL(S_G);  double* dG2 = c.SL(S_G2);
    double* dW  = c.SL(S_W);  double* dV  = c.SL(S_V);
    double* dLT = c.SL(S_LAT);
    double* dS  = c.SL(PBASE);
    double* EW  = c.SL(S_EW);
    const int ij2 = c.ij2;

    // A = B + I ; seed X0 = 0.75I - 0.25B (resid = 0.25(I-B)^2, small)
    dG[ij2] = EW[ij2] + (c.diagre ? 1.0 : 0.0);
    dX[ij2] = -0.25 * EW[ij2] + (c.diagre ? 0.75 : 0.0);
    c.GS();
    c.partials(dG, false);
    c.GS();
    double cn1, cninf;
    double* giy = c.inv(dG, 0.0, 40, 2, invBase, cn1, cninf);
    c.gemm(EW, giy, dW, 1,-1, 1,0, 1.0, 0.0, nullptr, 0,0, 0.0, nullptr); // W=(B-I)(B+I)^-1
    c.GS();
    c.gemm(dW, dW, dV, 1,0, 1,0, 1.0, 0.0, nullptr, 0,0, 0.0, nullptr);   // V = W^2
    c.partials(dW, false);                                 // ||W||inf for degree
    c.GS();
    double nW = c.bmax(NRM_ROW);
    double q = nW * nW;
    int J = 19;
    if (q < 0.5){
        J = 1;
        double qp = q * q;
        while (J < 19 && qp >= 1e-16 * (1.0 - q)){ qp *= q; J++; }
    }
    dG[ij2] = c.diagre ? 1.0/(double)(2*J + 1) : 0.0;      // Horner seed
    c.GS();
    double* gc = dG; double* go = dG2;
    for (int j = J - 1; j >= 0; j--){
        c.gemm(dV, gc, go, 1,0, 1,0, 1.0, 0.0, nullptr, 0,0, 1.0/(double)(2*j + 1), nullptr);
        c.GS();
        double* tm = gc; gc = go; go = tm;
    }
    c.gemm(dW, gc, dLT, 1,0, 1,0, 1.0, 0.0, nullptr, 0,0, 0.0, nullptr);  // LAT = artanh(W)
    c.GS();
    double vv = dLT[ij2] - dLT[c.tr_idx];
    dS[ij2] = c.pl ? -LOG_SCALE * vv : LOG_SCALE * vv;     // S = 32*conj(LAT-LAT^T)
}

// theta per u (rigorous upper bound); theta>4 -> scaling+squaring pool
__global__ __launch_bounds__(256) void k_theta_pool(double* ws)
{
    __shared__ double th[256]; __shared__ int rk[256];
    int t = threadIdx.x;
    double nS = ws[SC_NORMS2];
    double cr = ws[W_C_RE + t], ci = ws[W_C_IM + t];
    th[t] = sqrt(cr*cr + ci*ci) * nS;
    __syncthreads();
    int r = 0;
    for (int v = 0; v < 256; v++){
        if (th[v] > th[t] || (th[v] == th[t] && v < t)) r++;
    }
    rk[t] = r;
    __syncthreads();
    if (t == 0){
        int cnt = 0;
        for (int u = 0; u < 256; u++){
            double s = 0.0; int slot = -1;
            if (th[u] > 4.0 && rk[u] < NPOOL){
                double e = ceil(log2(th[u] / 4.0));
                if (e < 1.0) e = 1.0; if (e > 12.0) e = 12.0;
                s = e; slot = cnt;
                ws[W_SLOTU + cnt] = (double)u;
                cnt++;
            }
            ws[W_SU + u] = s;
            ws[W_SLOT + u] = (double)slot;
        }
        for (int k = cnt; k < NPOOL; k++) ws[W_SLOTU + k] = -1.0;
    }
}

// weights w[u][k] = (c_u / 2^{s_u})^k / k!
__global__ __launch_bounds__(256) void k_weights(double* ws)
{
    int u = threadIdx.x;
    double sc = ldexp(1.0, -(int)ws[W_SU + u]);
    double cr = ws[W_C_RE + u] * sc, ci = ws[W_C_IM + u] * sc;
    double wr = 1.0, wi = 0.0;
    ws[W_W + (u*33)*2] = 1.0; ws[W_W + (u*33)*2 + 1] = 0.0;
    for (int k = 1; k <= 32; k++){
        double inv = 1.0 / (double)k;
        double nr = (wr*cr - wi*ci) * inv, ni = (wr*ci + wi*cr) * inv;
        wr = nr; wi = ni;
        ws[W_W + (u*33 + k)*2] = wr;
        ws[W_W + (u*33 + k)*2 + 1] = wi;
    }
}

// exp_tens[u] = sum_k w[u][k] S^k -> f32 out (non-pooled) or fp64 pool base
__global__ __launch_bounds__(256) void k_combo(double* ws, float* out, long off_ex, int f,
                                               int pass, int K)
{
    __shared__ double wre[16][33], wim[16][33];
    __shared__ int anywork;
    int t = threadIdx.x;
    int row = blockIdx.x, ug = blockIdx.y;
    if (t == 0) anywork = (pass == 0) ? 1 : 0;
    __syncthreads();
    if (pass > 0 && t < 16){
        int u = ug*16 + t;
        int slot = (int)ws[W_SLOT + u];
        int phys = slot - pass * K;
        if (slot >= 0 && phys >= 0 && phys < K) anywork = 1;
    }
    __syncthreads();
    if (!anywork) return;
    for (int i = t; i < 16*33; i += 256){
        int g = i / 33, k = i % 33;
        int u = ug*16 + g;
        wre[g][k] = ws[W_W + (u*33 + k)*2];
        wim[g][k] = ws[W_W + (u*33 + k)*2 + 1];
    }
    __syncthreads();
    int j = t, ij = row*256 + j;
    double ar[16], ai[16];
    #pragma unroll
    for (int g = 0; g < 16; g++){
        ar[g] = (row == j) ? wre[g][0] : 0.0;
        ai[g] = (row == j) ? wim[g][0] : 0.0;
    }
    for (int k = 1; k <= 32; k++){
        const double* SP = ws + MAT0 + (size_t)(PBASE + k - 1) * MATD;
        double sre = SP[ij], sim = SP[NN + ij];
        #pragma unroll
        for (int g = 0; g < 16; g++){
            ar[g] += wre[g][k]*sre - wim[g][k]*sim;
            ai[g] += wre[g][k]*sim + wim[g][k]*sre;
        }
    }
    for (int g = 0; g < 16; g++){
        int u = ug*16 + g;
        int slot = (int)ws[W_SLOT + u];
        if (slot >= 0){
            int phys = slot - pass * K;
            if (phys >= 0 && phys < K){
                double* P = ws + MAT0 + (size_t)(POOL0 + phys) * MATD;
                P[ij] = ar[g]; P[NN + ij] = ai[g];
            }
        } else if (pass == 0){
            long base = off_ex + (long)u * NN * f + (long)ij * f;
            out[base] = (float)ar[g];
            if (f == 2) out[base + 1] = (float)ai[g];
        }
    }
}

// pool squaring
__global__ __launch_bounds__(256) void k_pool_sq(double* ws, int round, int pass, int K)
{
    int z = blockIdx.z;
    int vs = pass * K + z;
    int u = (vs < NPOOL) ? (int)ws[W_SLOTU + vs] : -1;
    if (u < 0) return;
    if (round > (int)ws[W_SU + u]) return;
    const double* A = ws + MAT0 + (size_t)(POOL0 + ((round & 1) ? 0 : K) + z) * MATD;
    double* C = ws + MAT0 + (size_t)(POOL0 + ((round & 1) ? K : 0) + z) * MATD;
    int tx = threadIdx.x & 15, ty = threadIdx.x >> 4;
    int row = blockIdx.y*16 + ty, col = blockIdx.x*16 + tx;
    __shared__ double Asr[16][17], Asi[16][17], Bsr[16][17], Bsi[16][17];
    double cr = 0.0, ci = 0.0;
    for (int k0 = 0; k0 < 256; k0 += 16){
        Asr[ty][tx] = A[row*256 + k0 + tx];
        Asi[ty][tx] = A[NN + row*256 + k0 + tx];
        Bsr[ty][tx] = A[(k0 + ty)*256 + col];
        Bsi[ty][tx] = A[NN + (k0 + ty)*256 + col];
        __syncthreads();
        #pragma unroll
        for (int kk = 0; kk < 16; kk++){
            double xr = Asr[ty][kk], xi = Asi[ty][kk];
            double yr = Bsr[kk][tx], yi = Bsi[kk][tx];
            cr += xr*yr - xi*yi;
            ci += xr*yi + xi*yr;
        }
        __syncthreads();
    }
    C[row*256 + col] = cr;
    C[NN + row*256 + col] = ci;
}

__global__ __launch_bounds__(256) void k_pool_out(const double* ws, float* out, long off_ex,
                                                  int f, int pass, int K)
{
    int z = blockIdx.y;
    int vs = pass * K + z;
    int u = (vs < NPOOL) ? (int)ws[W_SLOTU + vs] : -1;
    if (u < 0) return;
    int su = (int)ws[W_SU + u];
    int ij = blockIdx.x * 256 + threadIdx.x;
    const double* P = ws + MAT0 + (size_t)(POOL0 + ((su & 1) ? K : 0) + z) * MATD;
    long base = off_ex + (long)u * NN * f + (long)ij * f;
    out[base] = (float)P[ij];
    if (f == 2) out[base + 1] = (float)P[NN + ij];
}

__global__ __launch_bounds__(256) void k_cast_out(const double* ws, int slot, float* out, long off, int f)
{
    int ij = blockIdx.x * 256 + threadIdx.x;
    const double* P = ws + MAT0 + (size_t)slot * MATD;
    out[off + (long)ij * f] = (float)P[ij];
    if (f == 2) out[off + (long)ij * f + 1] = (float)P[NN + ij];
}

// ============================ host ============================
extern "C" void kernel_launch(void* const* d_in, const int* in_sizes, int n_in,
                              void* d_out, int out_size, void* d_ws, size_t ws_size,
                              hipStream_t stream)
{
    double* ws = (double*)d_ws;
    float* out = (float*)d_out;

    int f = (out_size >= 33816832) ? 2 : 1;
    long off_ex = 256;
    long off_uw = off_ex + (long)f * 16777216L;
    long off_ew = off_uw + (long)f * 65536L;

    k_init<<<128, 256, 0, stream>>>(ws);
    k_detect<<<1, 64, 0, stream>>>(d_in[0], ws);
    k_small<<<1, 256, 0, stream>>>(d_in[0], d_in[1], d_in[2], d_in[3], d_in[4], ws, out);

    long slotsAvail = (long)(ws_size / 8 - MAT0) / MATD;
    if (slotsAvail < POOL0 + 32) return;
    int K = (int)((slotsAvail - POOL0) / 2);
    if (K > NPOOL) K = NPOOL;
    if (K < 16) K = 16;
    int P = (NPOOL + K - 1) / K;

    auto MP = [&](int s){ return ws + MAT0 + (size_t)s * MATD; };
    auto ZG = [&](int a, int b, int c, int preA, int preB, double al, double be,
                  int d, double ga, int fm, int round){
        k_zgemm<<<dim3(16,16,1), 256, 0, stream>>>(MP(a), MP(b), MP(c),
            d >= 0 ? MP(d) : nullptr, preA, preB, al, be, ga, ws,
            fm, round, 0, 0, 0L, 0L, 0L);
    };
    auto GEMM = [&](int a, int b, int c, int preA, int preB, double al, double be, int d, double ga){
        ZG(a, b, c, preA, preB, al, be, d, ga, 0, 0);
    };

    k_build_mats<<<256, 256, 0, stream>>>(d_in[5], d_in[6], d_in[7], d_in[8], ws);
    k_cast_out<<<256, 256, 0, stream>>>(ws, S_NUW, out, off_uw, f);

    // -------- expm(new_uw): scaling + Paterson-Stockmeyer deg-16 Taylor + squarings ----
    static const double INVF[17] = {
        1.0, 1.0, 0.5, 1.0/6.0, 1.0/24.0, 1.0/120.0, 1.0/720.0, 1.0/5040.0,
        1.0/40320.0, 1.0/362880.0, 1.0/3628800.0, 1.0/39916800.0, 1.0/479001600.0,
        1.0/6227020800.0, 1.0/87178291200.0, 1.0/1307674368000.0, 1.0/20922789888000.0 };
    k_norm1inf<<<1, 256, 0, stream>>>(MP(S_NUW), ws, 8);
    k_expm_prep<<<1, 64, 0, stream>>>(ws);
    k_combine<<<256, 256, 0, stream>>>(ws, S_LAT, S_NUW, -1, -1, -1, 1.0, 0, 0, 0, 0.0, 1);
    GEMM(S_LAT, S_LAT, S_T2, 0, 0, 1.0, 0.0, -1, 0.0);
    GEMM(S_T2, S_LAT, S_T3, 0, 0, 1.0, 0.0, -1, 0.0);
    GEMM(S_T2, S_T2, S_T4, 0, 0, 1.0, 0.0, -1, 0.0);
    k_combine<<<256, 256, 0, stream>>>(ws, S_E1, -1, -1, -1, -1, 0, 0, 0, 0, INVF[16], 0);
    for (int b = 3; b >= 0; b--){
        GEMM(S_T4, S_E1, S_E2, 0, 0, 1.0, 0.0, -1, 0.0);
        k_combine<<<256, 256, 0, stream>>>(ws, S_E1, S_E2, S_LAT, S_T2, S_T3,
            1.0, INVF[4*b+1], INVF[4*b+2], INVF[4*b+3], INVF[4*b], 0);
    }
    for (int r = 1; r <= 10; r++){
        int src = (r & 1) ? S_E1 : S_E2, dst = (r & 1) ? S_E2 : S_E1;
        ZG(src, src, dst, 0, 0, 1.0, 0.0, -1, 0.0, 1, r);
    }
    GEMM(S_EW, S_E1, S_M2, 1, 0, 1.0, 0.0, -1, 0.0);   // new_Ew = conj(Ew) expm(new_uw)
    k_cast_out<<<256, 256, 0, stream>>>(ws, S_M2, out, off_ew, f);

    // -------- logm(Ew): 5 cooperative stage launches (rocprof per-stage rows) ----
    {
        int ib0 = 0, ib1 = 20, ib2 = 40;
        { void* a[] = { (void*)&ws, (void*)&ib0 };
          hipLaunchCooperativeKernel((void*)k_logm_db, dim3(256), dim3(512), a, 0, stream); }
        { void* a[] = { (void*)&ws, (void*)&ib1 };
          hipLaunchCooperativeKernel((void*)k_logm_db, dim3(256), dim3(512), a, 0, stream); }
        { void* a[] = { (void*)&ws };
          hipLaunchCooperativeKernel((void*)k_logm_sq, dim3(256), dim3(512), a, 0, stream); }
        { void* a[] = { (void*)&ws };
          hipLaunchCooperativeKernel((void*)k_logm_sq, dim3(256), dim3(512), a, 0, stream); }
        { void* a[] = { (void*)&ws, (void*)&ib2 };
          hipLaunchCooperativeKernel((void*)k_logm_cay, dim3(256), dim3(512), a, 0, stream); }
    }

    // -------- batched exp_tens = expm(c_u S): shared powers + pooled squaring --------
    k_norm1inf<<<1, 256, 0, stream>>>(MP(PBASE), ws, 12);
    k_fro<<<1, 256, 0, stream>>>(MP(PBASE), ws);
    k_snorm<<<1, 1, 0, stream>>>(ws);
    k_theta_pool<<<1, 256, 0, stream>>>(ws);
    k_weights<<<1, 256, 0, stream>>>(ws);
    for (int m = 1; m < 32; m *= 2){
        int cnt = (m < 32 - m) ? m : (32 - m);
        k_zgemm<<<dim3(16,16,cnt), 256, 0, stream>>>(MP(PBASE + m - 1), MP(PBASE), MP(PBASE + m),
            nullptr, 0, 0, 1.0, 0.0, 0.0, ws, 0, 0, 0, 0, 0L, MATD, MATD);
    }
    for (int p = 0; p < P; p++){
        k_combo<<<dim3(256,16), 256, 0, stream>>>(ws, out, off_ex, f, p, K);
        for (int r = 1; r <= 12; r++)
            k_pool_sq<<<dim3(16,16,K), 256, 0, stream>>>(ws, r, p, K);
        k_pool_out<<<dim3(256,K), 256, 0, stream>>>(ws, out, off_ex, f, p, K);
    }
}

// Round 10
// 11601.781 us; speedup vs baseline: 1.6373x; 1.0005x over previous
//
#include <hip/hip_runtime.h>
#include <hip/hip_bf16.h>
#include <math.h>

#define NN 65536
#define MATD 131072L   // doubles per complex matrix (re plane + im plane)
#define MAT0 32768L    // header size in doubles

// ws header offsets (doubles)
#define SC_DT 0
#define SC_NUINV 3
#define SC_EXPM_S 4
#define SC_EXPM_SCALE 5
#define SC_NORMS2 6
#define SC_MU 7
// 8,9: n1,ninf of M ; 12,13: n1,ninf of S ; 14: F^2 of S
#define W_UNIT_RE 64
#define W_UNIT_IM 320
#define W_C_RE 576
#define W_C_IM 832
#define W_LD_RE 1088
#define W_LD_IM 1344
#define W_SU 1600
#define W_SLOT 1856
#define W_SLOTU 2112        // 256 entries -> ends 2368
#define W_W 2432            // 256*33*2 doubles -> ends 19328
#define BARB 19456          // barrier: page q at +q*512 (arrive +0, gen line +16: gen,u32 pad, pay0, pay1)
#define BARM 23552          // master line (own page)
#define TRBASE 24064        // 128 doubles per inversion (41 inversions -> ends 29312)
#define B_INF0 29440        // double-buffered row inf-sums (256 each)
#define B_INF1 29696
#define B_DEV0 29952        // double-buffered row |M-I| sums
#define B_DEV1 30208
#define XNRM 30720          // rows-only inf sums of iy (256)
#define NRM_ROW 31872       // classic partials: 256 row sums
#define NRM_COL 32128       // classic partials: 256 col sums
#define NPOOL 256           // virtual pool capacity

// matrix slots
#define S_EW 0
#define S_NUW 1
#define S_LAT 2
#define S_T2 3
#define S_T3 4
#define S_T4 5
#define S_E1 6
#define S_E2 7
#define S_M 8
#define S_M2 9
#define S_Y 10
#define S_Y2 11
#define S_IY 12
#define S_X 13
#define S_X2 14
#define S_T 15
#define S_W 16
#define S_V 17
#define S_G 18
#define S_G2 19
#define PBASE 20            // S^k at PBASE+k-1, k=1..32 -> 20..51
#define POOL0 52            // physical pool

#define PI_D 3.14159265358979323846
#define LOG_SCALE 32.0      // 2 * 2^4 sqrt stages (2 DB + 2 NS-sqrt)

__device__ inline double ldin(const void* p, int i, int dt){
    if (dt == 0) return (double)__bfloat162float(((const __hip_bfloat16*)p)[i]);
    if (dt == 1) return (double)((const float*)p)[i];
    return ((const double*)p)[i];
}

// ---------------- init: zero header ----------------
__global__ __launch_bounds__(256) void k_init(double* ws){
    ws[blockIdx.x * 256 + threadIdx.x] = 0.0;   // grid 128 -> 32768
}

// ---------------- input dtype detection ----------------
__global__ __launch_bounds__(64) void k_detect(const void* x, double* ws){
    __shared__ int ok[3];
    int t = threadIdx.x;
    if (t < 3) ok[t] = 1;
    __syncthreads();
    const __hip_bfloat16* pb = (const __hip_bfloat16*)x;
    for (int k = t; k < 256; k += 64){
        float v = __bfloat162float(pb[k]);
        if (!(v > 0.40f && v < 1.60f)) ok[0] = 0;
    }
    const float* pf = (const float*)x;
    { float v = pf[t]; if (!(v > 0.40f && v < 1.60f)) ok[1] = 0; }
    const double* pd = (const double*)x;
    { double v = pd[t]; if (!(v > 0.40 && v < 1.60)) ok[2] = 0; }
    __syncthreads();
    if (t == 0) ws[SC_DT] = ok[0] ? 0.0 : (ok[1] ? 1.0 : 2.0);
}

// ---------------- small vector stage (1 block) ----------------
__global__ __launch_bounds__(256) void k_small(
    const void* xin, const void* Ar, const void* Ai,
    const void* cAr, const void* cAi,
    double* ws, float* out)
{
    __shared__ double xs[256], twc[256], tws[256], ur[256], ui[256], red[256];
    int t = threadIdx.x;
    int dt = (int)ws[SC_DT];
    double x = ldin(xin, t, dt);
    xs[t] = x;
    red[t] = log(x);
    double ang = -2.0 * PI_D * (double)t / 256.0;
    twc[t] = cos(ang); tws[t] = sin(ang);
    __syncthreads();
    for (int s = 128; s > 0; s >>= 1){ if (t < s) red[t] += red[t+s]; __syncthreads(); }
    double slog = red[0];
    __syncthreads();
    double dy = (t == 0) ? 0.0 : (x - xs[t-1]);
    double r = x * exp(-slog / 256.0);
    double unr = r * cos(dy), uni = r * sin(dy);
    ur[t] = unr; ui[t] = uni;
    ws[W_UNIT_RE + t] = unr; ws[W_UNIT_IM + t] = uni;
    __syncthreads();
    double fr = 0.0, fi = 0.0;
    for (int n = 0; n < 256; n++){
        int m = (t * n) & 255;
        double c = twc[m], s = tws[m];
        fr += ur[n]*c - ui[n]*s;
        fi += ur[n]*s + ui[n]*c;
    }
    red[t] = fr; __syncthreads();
    for (int s = 128; s > 0; s >>= 1){ if (t < s) red[t] += red[t+s]; __syncthreads(); }
    double sr = red[0]; __syncthreads();
    red[t] = fi; __syncthreads();
    for (int s = 128; s > 0; s >>= 1){ if (t < s) red[t] += red[t+s]; __syncthreads(); }
    double si = red[0];
    double den = sr*sr + si*si;
    double cr = (fr*sr + fi*si) / den, ci = (fi*sr - fr*si) / den;
    ws[W_C_RE + t] = cr; ws[W_C_IM + t] = ci;
    double ar = ldin(Ar, t, dt), ai = ldin(Ai, t, dt);
    double car = ldin(cAr, t, dt), cai = ldin(cAi, t, dt);
    double pr = ar*unr - ai*uni, pi = ar*uni + ai*unr;
    double qr = car*pr + cai*pi, qi = car*pi - cai*pr;
    out[t] = (float)(x + atan2(qi, qr));
    double ldr = 0.5 * log((qr*qr + qi*qi) / (unr*unr + uni*uni));
    double ldi = atan2(qi, qr) - atan2(uni, unr);
    ws[W_LD_RE + t] = ldr; ws[W_LD_IM + t] = ldi;
}

// ---------------- build Ew and new_uw (fp64 planes) ----------------
__global__ __launch_bounds__(256) void k_build_mats(
    const void* Ewr, const void* Ewi, const void* uwr, const void* uwi, double* ws)
{
    int ij = blockIdx.x * 256 + threadIdx.x;
    int i = ij >> 8, j = ij & 255;
    int dt = (int)ws[SC_DT];
    double* EW = ws + MAT0 + (size_t)S_EW * MATD;
    EW[ij] = ldin(Ewr, ij, dt); EW[NN + ij] = ldin(Ewi, ij, dt);
    double* U = ws + MAT0 + (size_t)S_NUW * MATD;
    if (i == 0){ U[ij] = ws[W_LD_RE + j]; U[NN + ij] = ws[W_LD_IM + j]; }
    else { int src = (i-1)*256 + j; U[ij] = ldin(uwr, src, dt); U[NN + ij] = ldin(uwi, src, dt); }
}

// ---------------- norms: ws[idx]=n1, ws[idx+1]=ninf ----
__global__ __launch_bounds__(256) void k_norm1inf(const double* M, double* ws, int idx)
{
    __shared__ double cs[256], rs[256];
    int t = threadIdx.x;
    double c = 0.0, r = 0.0;
    for (int i = 0; i < 256; i++){
        c += fabs(M[i*256 + t]) + fabs(M[NN + i*256 + t]);
        r += fabs(M[t*256 + i]) + fabs(M[NN + t*256 + i]);
    }
    cs[t] = c; rs[t] = r; __syncthreads();
    for (int s = 128; s > 0; s >>= 1){
        if (t < s){ cs[t] = fmax(cs[t], cs[t+s]); rs[t] = fmax(rs[t], rs[t+s]); }
        __syncthreads();
    }
    if (t == 0){
        ws[idx] = cs[0]; ws[idx+1] = rs[0];
        ws[SC_NUINV] = 1.0 / (cs[0] * rs[0]);
    }
}

// Frobenius^2 -> ws[14]
__global__ __launch_bounds__(256) void k_fro(const double* M, double* ws)
{
    __shared__ double red[256];
    int t = threadIdx.x;
    double s = 0.0;
    for (int i = 0; i < 256; i++){
        double a = M[i*256 + t], b = M[NN + i*256 + t];
        s += a*a + b*b;
    }
    red[t] = s; __syncthreads();
    for (int k = 128; k > 0; k >>= 1){ if (t < k) red[t] += red[t+k]; __syncthreads(); }
    if (t == 0) ws[14] = red[0];
}

// rigorous sigma_max upper bound: min( sqrt(n1*ninf), ||S||_F )
__global__ void k_snorm(double* ws)
{
    double b1 = sqrt(ws[12] * ws[13]);
    double b2 = sqrt(ws[14]);
    ws[SC_NORMS2] = fmin(b1, b2);
}

// ---------------- complex GEMM (host-launched; expm + powers path) ----------------
__global__ __launch_bounds__(256) void k_zgemm(
    const double* __restrict__ Ab, const double* __restrict__ Bb,
    double* __restrict__ Cb, const double* __restrict__ Db,
    int preA, int preB, double alpha, double beta, double gamma,
    double* __restrict__ ws, int fm, int round, int flagIdx, int trIdx,
    long sA, long sB, long sC)
{
    int z = blockIdx.z;
    const double* A = Ab + (size_t)z * sA;
    const double* B = Bb + (size_t)z * sB;
    double* C = Cb + (size_t)z * sC;
    int tx = threadIdx.x & 15, ty = threadIdx.x >> 4;
    int row = blockIdx.y * 16 + ty, col = blockIdx.x * 16 + tx;
    if (fm == 1 && round > (int)ws[SC_EXPM_S]){
        C[row*256 + col] = A[row*256 + col];
        C[NN + row*256 + col] = A[NN + row*256 + col];
        return;
    }
    __shared__ double Asr[16][17], Asi[16][17], Bsr[16][17], Bsi[16][17];
    double cr = 0.0, ci = 0.0;
    for (int k0 = 0; k0 < 256; k0 += 16){
        int ac = k0 + tx;
        double a_re = A[row*256 + ac], a_im = A[NN + row*256 + ac];
        if (preA == 1) a_im = -a_im;
        else if (preA == 2){ if (row == ac) a_re -= 1.0; }
        int br = k0 + ty;
        double b_re = B[br*256 + col], b_im = B[NN + br*256 + col];
        if (preB == 1){ b_re = ((br == col) ? 2.0 : 0.0) - b_re; b_im = -b_im; }
        Asr[ty][tx] = a_re; Asi[ty][tx] = a_im;
        Bsr[ty][tx] = b_re; Bsi[ty][tx] = b_im;
        __syncthreads();
        #pragma unroll
        for (int kk = 0; kk < 16; kk++){
            double xr = Asr[ty][kk], xi = Asi[ty][kk];
            double yr = Bsr[kk][tx], yi = Bsi[kk][tx];
            cr += xr*yr - xi*yi;
            ci += xr*yi + xi*yr;
        }
        __syncthreads();
    }
    double outr = alpha * cr, outi = alpha * ci;
    if (Db){ outr += beta * Db[row*256 + col]; outi += beta * Db[NN + row*256 + col]; }
    if (row == col) outr += gamma;
    C[row*256 + col] = outr;
    C[NN + row*256 + col] = outi;
}

// ---- elementwise combine (expm path) ----
__global__ __launch_bounds__(256) void k_combine(double* ws, int dst,
    int s1, int s2, int s3, int s4,
    double a1, double a2, double a3, double a4, double g, int mode)
{
    int ij = blockIdx.x * 256 + threadIdx.x;
    int i = ij >> 8, j = ij & 255;
    double f1 = 1.0, f2 = 1.0;
    if (mode == 1){ f1 = ws[SC_EXPM_SCALE]; }
    double* C = ws + MAT0 + (size_t)dst * MATD;
    double r = 0.0, m = 0.0;
    if (s1 >= 0){ const double* X = ws + MAT0 + (size_t)s1 * MATD; r += a1*f1*X[ij]; m += a1*f1*X[NN+ij]; }
    if (s2 >= 0){ const double* X = ws + MAT0 + (size_t)s2 * MATD; r += a2*f2*X[ij]; m += a2*f2*X[NN+ij]; }
    if (s3 >= 0){ const double* X = ws + MAT0 + (size_t)s3 * MATD; r += a3*X[ij]; m += a3*X[NN+ij]; }
    if (s4 >= 0){ const double* X = ws + MAT0 + (size_t)s4 * MATD; r += a4*X[ij]; m += a4*X[NN+ij]; }
    if (i == j) r += g;
    C[ij] = r; C[NN + ij] = m;
}

__global__ void k_expm_prep(double* ws)
{
    if (threadIdx.x == 0 && blockIdx.x == 0){
        double n1 = ws[8];
        int s = 0;
        if (n1 > 0.5){
            s = (int)ceil(log2(n1 / 0.5));
            if (s < 0) s = 0; if (s > 10) s = 10;
        }
        ws[SC_EXPM_S] = (double)s;
        ws[SC_EXPM_SCALE] = ldexp(1.0, -s);
    }
}

// ==================== cooperative logm machinery ====================
// 256 blocks x 512 threads. Register-batched gemm loads; barrier with
// piggybacked 2-double payload (trace); fused row-sum epilogues replace
// separate partials phases in the DB/sq inner loops.
struct ShMemC {
    double Ar[2][16][17], Ai[2][16][17], Br[2][16][17], Bi[2][16][17];
    double redB[256];
    double trR[16], trI[16];
    double pay0, pay1;
};

struct GOp {
    const double* A; const double* B; double* C;
    double sA, dA, sB, dB;        // operands: (sA*A + dA*I), (sB*B + dB*I)
    double alpha, beta;           // C = alpha*AB + beta*(sD*D + dD*I) + gamma*I
    const double* D; double sD, dD;
    double gamma;
    double* tr;                   // trace accumulator (only honored on op0)
};

struct Ctx {
    double* ws; ShMemC* sh;
    unsigned int bgen;
    int t, b, team, tt, tx, ty, bx, by, row, col, ij2, pl, li, lj, tr_idx;
    bool diagre;

    __device__ void init(double* ws_, ShMemC* sh_){
        ws = ws_; sh = sh_;
        t = threadIdx.x; b = blockIdx.x;
        team = t >> 8; tt = t & 255;
        tx = tt & 15; ty = tt >> 4;
        bx = b & 15; by = b >> 4;
        row = by*16 + ty; col = bx*16 + tx;
        ij2 = b*512 + t;
        pl = ij2 >> 16;
        int lin = ij2 & 65535;
        li = lin >> 8; lj = lin & 255;
        tr_idx = (lj << 8) + li + (pl ? NN : 0);
        diagre = (pl == 0) && (li == lj);
        bgen = __hip_atomic_load((unsigned int*)(ws + BARB + 16), __ATOMIC_RELAXED,
                                 __HIP_MEMORY_SCOPE_AGENT);
    }
    __device__ double* SL(int s){ return ws + MAT0 + (size_t)s * MATD; }

    __device__ void spinwait(unsigned int* gline, unsigned int g){
        while (__hip_atomic_load(gline, __ATOMIC_RELAXED,
                                 __HIP_MEMORY_SCOPE_AGENT) == g)
            __builtin_amdgcn_s_sleep(2);
        if (__hip_atomic_load(gline, __ATOMIC_ACQUIRE,
                              __HIP_MEMORY_SCOPE_AGENT) == g)
            __builtin_amdgcn_s_sleep(1);
    }

    // grid barrier with optional 2-double payload broadcast (e.g. trace).
    // Master reads pay[0..1] once and stores them into each group's gen
    // cacheline BEFORE the gen release; spinners read them with the poll.
    __device__ void GS(const double* pay){
        __syncthreads();
        if (t == 0){
            unsigned int g = bgen;
            int grp = b & 7;
            unsigned int* aline  = (unsigned int*)(ws + BARB + grp*512);
            unsigned int* gline  = (unsigned int*)(ws + BARB + grp*512 + 16);
            unsigned int* master = (unsigned int*)(ws + BARM);
            double p0 = 0.0, p1 = 0.0;
            unsigned int a = __hip_atomic_fetch_add(aline, 1u, __ATOMIC_ACQ_REL,
                                                    __HIP_MEMORY_SCOPE_AGENT);
            if (a == 31u){
                unsigned int m = __hip_atomic_fetch_add(master, 1u, __ATOMIC_ACQ_REL,
                                                        __HIP_MEMORY_SCOPE_AGENT);
                if (m == 7u){
                    __hip_atomic_store(master, 0u, __ATOMIC_RELAXED, __HIP_MEMORY_SCOPE_AGENT);
                    if (pay){ p0 = pay[0]; p1 = pay[1]; }
                    for (int q = 0; q < 8; q++){
                        __hip_atomic_store((unsigned int*)(ws + BARB + q*512), 0u,
                                           __ATOMIC_RELAXED, __HIP_MEMORY_SCOPE_AGENT);
                        if (pay){
                            ws[BARB + q*512 + 17] = p0;
                            ws[BARB + q*512 + 18] = p1;
                        }
                    }
                    for (int q = 0; q < 8; q++)
                        __hip_atomic_store((unsigned int*)(ws + BARB + q*512 + 16), g + 1u,
                                           __ATOMIC_RELEASE, __HIP_MEMORY_SCOPE_AGENT);
                } else {
                    spinwait(gline, g);
                    if (pay){ p0 = ws[BARB + grp*512 + 17]; p1 = ws[BARB + grp*512 + 18]; }
                }
            } else {
                spinwait(gline, g);
                if (pay){ p0 = ws[BARB + grp*512 + 17]; p1 = ws[BARB + grp*512 + 18]; }
            }
            if (pay){ sh->pay0 = p0; sh->pay1 = p1; }
        }
        __syncthreads();
        bgen++;
    }

    // grid-uniform max over a 256-entry ws array (shfl + LDS)
    __device__ double bmax(int base){
        double v = ws[base + (t & 255)];
        #pragma unroll
        for (int m = 32; m >= 1; m >>= 1) v = fmax(v, __shfl_xor(v, m));
        if ((t & 63) == 0) sh->redB[t >> 6] = v;
        __syncthreads();
        double u = sh->redB[0];
        #pragma unroll
        for (int q = 1; q < 8; q++) u = fmax(u, sh->redB[q]);
        __syncthreads();
        return u;
    }

    // classic partials: block b computes row-b abs sums (rowDst), optionally
    // col-b sums (colDst>=0) and |row - I| sums (devDst>=0).
    __device__ void partials(const double* M, int rowDst, int colDst, int devDst){
        double v = 0.0, dv = 0.0;
        if (t < 256){
            double e = M[b*256 + t], f2 = M[NN + b*256 + t];
            v = fabs(e) + fabs(f2);
            if (devDst >= 0) dv = fabs(e - ((b == t) ? 1.0 : 0.0)) + fabs(f2);
        } else if (colDst >= 0){
            int c2 = t - 256;
            v = fabs(M[c2*256 + b]) + fabs(M[NN + c2*256 + b]);
        }
        #pragma unroll
        for (int m = 32; m >= 1; m >>= 1){ v += __shfl_xor(v, m); dv += __shfl_xor(dv, m); }
        if ((t & 63) == 0){ sh->redB[t >> 6] = v; sh->redB[8 + (t >> 6)] = dv; }
        __syncthreads();
        if (t == 0){
            ws[rowDst + b] = sh->redB[0] + sh->redB[1] + sh->redB[2] + sh->redB[3];
            if (devDst >= 0)
                ws[devDst + b] = sh->redB[8] + sh->redB[9] + sh->redB[10] + sh->redB[11];
        }
        if (t == 256 && colDst >= 0){
            ws[colDst + b] = sh->redB[4] + sh->redB[5] + sh->redB[6] + sh->redB[7];
        }
        __syncthreads();
    }

    // C = alpha*(sA*A+dA*I)(sB*B+dB*I) + beta*(sD*D+dD*I) + gamma*I.
    // split-k x2 across teams; ALL 8 k-steps' operands loaded in one burst.
    // devW: fused |C - I| row sums (atomicAdd); devZ: zero the other bank.
    __device__ void gemm(const double* A, const double* B, double* C,
                         double sA, double dA, double sB, double dB,
                         double alpha, double beta, const double* D,
                         double sD, double dD, double gamma, double* tr,
                         double* devW, double* devZ){
        double lar[8], lai[8], lbr[8], lbi[8];
        const double* Arow = A + (size_t)row*256;
        const double* Bcol = B + col;
        #pragma unroll
        for (int s = 0; s < 8; s++){
            int kb = (team << 7) + (s << 4);
            lar[s] = Arow[kb + tx];
            lai[s] = Arow[NN + kb + tx];
            lbr[s] = Bcol[(size_t)(kb + ty)*256];
            lbi[s] = Bcol[(size_t)NN + (size_t)(kb + ty)*256];
        }
        {   // pin the burst: force all loads complete before compute begins
            double dm = 0.0;
            #pragma unroll
            for (int s = 0; s < 8; s++) dm += lar[s] + lai[s] + lbr[s] + lbi[s];
            asm volatile("" :: "v"(dm));
        }
        double cr = 0.0, ci = 0.0;
        #pragma unroll
        for (int s = 0; s < 8; s++){
            int kb = (team << 7) + (s << 4);
            int ac = kb + tx, brx = kb + ty;
            sh->Ar[team][ty][tx] = sA * lar[s] + ((row == ac) ? dA : 0.0);
            sh->Ai[team][ty][tx] = sA * lai[s];
            sh->Br[team][ty][tx] = sB * lbr[s] + ((brx == col) ? dB : 0.0);
            sh->Bi[team][ty][tx] = sB * lbi[s];
            __syncthreads();
            #pragma unroll
            for (int kk = 0; kk < 16; kk++){
                double xr = sh->Ar[team][ty][kk], xi = sh->Ai[team][ty][kk];
                double yr = sh->Br[team][kk][tx], yi = sh->Bi[team][kk][tx];
                cr += xr*yr - xi*yi;
                ci += xr*yi + xi*yr;
            }
            __syncthreads();
        }
        if (team == 1){ sh->Ar[1][ty][tx] = cr; sh->Ai[1][ty][tx] = ci; }
        __syncthreads();
        if (team == 0){
            cr += sh->Ar[1][ty][tx]; ci += sh->Ai[1][ty][tx];
            cr *= alpha; ci *= alpha;
            if (D){
                cr += beta * (sD * D[row*256 + col] + ((row == col) ? dD : 0.0));
                ci += beta * (sD * D[NN + row*256 + col]);
            }
            if (row == col) cr += gamma;
            C[row*256 + col] = cr;
            C[NN + row*256 + col] = ci;
        }
        if (devW){
            double v = 0.0;
            if (team == 0) v = fabs(cr - ((row == col) ? 1.0 : 0.0)) + fabs(ci);
            #pragma unroll
            for (int m = 1; m < 16; m <<= 1) v += __shfl_xor(v, m);
            if (team == 0 && tx == 0) atomicAdd(&devW[row], v);
            if (team == 1 && tt < 16) devZ[by*16 + tt] = 0.0;
        }
        if (tr && bx == by){
            if (team == 0 && ty == tx){ sh->trR[ty] = cr; sh->trI[ty] = ci; }
            __syncthreads();
            if (t == 0){
                double sr = 0.0, si = 0.0;
                for (int q = 0; q < 16; q++){ sr += sh->trR[q]; si += sh->trI[q]; }
                atomicAdd(tr, sr); atomicAdd(tr + 1, si);
            }
        }
        __syncthreads();
    }

    // Two INDEPENDENT gemms concurrently (team0 -> o0, team1 -> o1), each at
    // full k-depth; ALL 16 k-steps' operands loaded in one burst.
    __device__ void gemm2(const GOp& o0, const GOp& o1){
        const GOp& d = team ? o1 : o0;
        double lar[16], lai[16], lbr[16], lbi[16];
        const double* Arow = d.A + (size_t)row*256;
        const double* Bcol = d.B + col;
        #pragma unroll
        for (int s = 0; s < 16; s++){
            int kb = s << 4;
            lar[s] = Arow[kb + tx];
            lai[s] = Arow[NN + kb + tx];
            lbr[s] = Bcol[(size_t)(kb + ty)*256];
            lbi[s] = Bcol[(size_t)NN + (size_t)(kb + ty)*256];
        }
        {
            double dm = 0.0;
            #pragma unroll
            for (int s = 0; s < 16; s++) dm += lar[s] + lai[s] + lbr[s] + lbi[s];
            asm volatile("" :: "v"(dm));
        }
        double cr = 0.0, ci = 0.0;
        #pragma unroll
        for (int s = 0; s < 16; s++){
            int kb = s << 4;
            int ac = kb + tx, brx = kb + ty;
            sh->Ar[team][ty][tx] = d.sA * lar[s] + ((row == ac) ? d.dA : 0.0);
            sh->Ai[team][ty][tx] = d.sA * lai[s];
            sh->Br[team][ty][tx] = d.sB * lbr[s] + ((brx == col) ? d.dB : 0.0);
            sh->Bi[team][ty][tx] = d.sB * lbi[s];
            __syncthreads();
            #pragma unroll
            for (int kk = 0; kk < 16; kk++){
                double xr = sh->Ar[team][ty][kk], xi = sh->Ai[team][ty][kk];
                double yr = sh->Br[team][kk][tx], yi = sh->Bi[team][kk][tx];
                cr += xr*yr - xi*yi;
                ci += xr*yi + xi*yr;
            }
            __syncthreads();
        }
        cr *= d.alpha; ci *= d.alpha;
        if (d.D){
            cr += d.beta * (d.sD * d.D[row*256 + col] + ((row == col) ? d.dD : 0.0));
            ci += d.beta * (d.sD * d.D[NN + row*256 + col]);
        }
        if (row == col) cr += d.gamma;
        d.C[row*256 + col] = cr;
        d.C[NN + row*256 + col] = ci;
        if (o0.tr && bx == by){
            if (team == 0 && ty == tx){ sh->trR[ty] = cr; sh->trI[ty] = ci; }
            __syncthreads();
            if (t == 0){
                double sr = 0.0, si = 0.0;
                for (int q = 0; q < 16; q++){ sr += sh->trR[q]; si += sh->trI[q]; }
                atomicAdd(o0.tr, sr); atomicAdd(o0.tr + 1, si);
            }
        }
        __syncthreads();
    }

    // NS inverse of A in R-X form; trace piggybacked on barriers.
    // mode 0: warm (dev<0.95): X0 = 2I-A synthesized; cold: explicit partials
    //   phase + scaled-Newton (cond/4 per iter).
    // mode 2: seeded (caller pre-wrote S_X and grid-synced; classic NRM arrays
    //   filled by caller for the fallback), trace-monitored cold fallback.
    // Exit: |tr(R)| < 1e-5.
    __device__ double* inv(const double* A, double dev, int maxit, int mode, int invid){
        double* X  = SL(S_X);  double* X2 = SL(S_X2);
        double* R  = SL(S_T);  double* R2 = SL(S_IY);
        bool scaled = false; double a = 1e-7;
        bool virt = false;
        double n1 = 0.0, ninf = 0.0;
        double* trb = ws + TRBASE + (size_t)invid * 128;   // pre-zeroed slots
        if (mode == 0){
            if (dev < 0.95){
                virt = true;   // R0 = I - A(2I - A), X0 synthesized
                gemm(A, A, R, 1,0, -1,2, -1.0, 0.0, nullptr, 0,0, 1.0, trb,
                     nullptr, nullptr);
            } else {
                partials(A, NRM_ROW, NRM_COL, -1);        // cold needs norms
                GS(nullptr);
                n1 = bmax(NRM_COL); ninf = bmax(NRM_ROW);
                scaled = true;
                double al = 1.0 / (n1 * ninf);
                double v = A[tr_idx] * al;
                X[ij2] = pl ? -v : v;                     // X0 = conj(A)^T/(n1*ninf)
                GS(nullptr);
                gemm(A, X, R, 1,0, 1,0, -1.0, 0.0, nullptr, 0,0, 1.0, trb,
                     nullptr, nullptr);
            }
        } else {
            n1 = bmax(NRM_COL); ninf = bmax(NRM_ROW);     // for fallback
            gemm(A, X, R, 1,0, 1,0, -1.0, 0.0, nullptr, 0,0, 1.0, trb,
                 nullptr, nullptr);
        }
        GS(trb);
        double resid = fabs(sh->pay0) + fabs(sh->pay1);
        double* xc = X; double* xo = X2; double* rc = R; double* ro = R2;
        bool canFall = (mode == 2);
        for (int i = 0; i < maxit; i++){
            if (resid < 1e-5){
                if (virt){   // converged at X0 (rare): materialize it
                    double v = -A[ij2];
                    if (diagre) v += 2.0;
                    xc[ij2] = v;
                    GS(nullptr);
                }
                break;
            }
            if (canFall && i >= 4 && resid > 1e4){
                // seeded start diverging -> rigorous cold restart
                canFall = false; scaled = true; a = 1e-7;
                double al = 1.0 / (n1 * ninf);
                double v = A[tr_idx] * al;
                xo[ij2] = pl ? -v : v;
                GS(nullptr);
                gemm(A, xo, ro, 1,0, 1,0, -1.0, 0.0, nullptr, 0,0, 1.0,
                     trb + 2*(i+1), nullptr, nullptr);
                GS(trb + 2*(i+1));
                resid = fabs(sh->pay0) + fabs(sh->pay1);
                double* tm = xc; xc = xo; xo = tm;
                tm = rc; rc = ro; ro = tm;
                continue;
            }
            double xi_ = 1.0;
            if (scaled){
                if (a > 0.5) scaled = false;
                else { xi_ = 2.0/(1.0 + a); double o = 1.0 + a; a = 4.0*a/(o*o); }
            }
            double omx = 1.0 - xi_;
            // team0: R' = ((1-xi)I + xi R)^2 (+trace) ; team1: X' = xi^2 XR + xi(2-xi) X
            GOp oR = { rc, rc, ro, xi_, omx, xi_, omx, 1.0, 0.0, nullptr, 0,0, 0.0,
                       trb + 2*(i+1) };
            GOp oX;
            if (virt){
                oX = GOp{ A, rc, xo, -1.0, 2.0, 1,0, xi_*xi_, xi_*(2.0 - xi_),
                          A, -1.0, 2.0, 0.0, nullptr };
                virt = false;
            } else {
                oX = GOp{ xc, rc, xo, 1,0, 1,0, xi_*xi_, xi_*(2.0 - xi_),
                          xc, 1.0, 0.0, 0.0, nullptr };
            }
            gemm2(oR, oX);
            GS(trb + 2*(i+1));
            resid = fabs(sh->pay0) + fabs(sh->pay1);
            double* tm = xc; xc = xo; xo = tm;
            tm = rc; rc = ro; ro = tm;
        }
        return xc;
    }
};

// ---- stage: one scaled product-form DB sqrt pass: S_EW <- sqrt(S_EW) ----
// Fused M' epilogue: dev/inf row sums into double-buffered banks.
__global__ __launch_bounds__(512, 1) void k_logm_db(double* __restrict__ ws, int invBase)
{
    __shared__ ShMemC sh;
    Ctx c; c.init(ws, &sh);
    double* dMm = c.SL(S_M);  double* dM2 = c.SL(S_M2);
    double* dYy = c.SL(S_Y);  double* dY2 = c.SL(S_Y2);
    double* dG  = c.SL(S_G);
    double* EW  = c.SL(S_EW);
    const int ij2 = c.ij2;

    dMm[ij2] = EW[ij2];
    dYy[ij2] = EW[ij2];
    c.partials(EW, B_INF0, -1, B_DEV0);
    if (c.t == 0){ ws[B_INF1 + c.b] = 0.0; ws[B_DEV1 + c.b] = 0.0; }
    c.GS(nullptr);
    double* mc = dMm; double* mo = dM2; double* yc = dYy; double* yo = dY2;
    int cur = 0;
    double dev = c.bmax(B_DEV0);
    double nm  = c.bmax(B_INF0);
    int invid = invBase;
    for (int it = 0; it < 20; it++){
        if (dev < 1e-7) break;
        double* iy = c.inv(mc, dev, 40, 0, invid++);
        // phase: G = Y * M^-1  +  rows-only inf sums of M^-1 (for mu)
        c.gemm(yc, iy, dG, 1,0, 1,0, 1.0, 0.0, nullptr, 0,0, 0.0, nullptr,
               nullptr, nullptr);
        c.partials(iy, XNRM, -1, -1);
        c.GS(nullptr);
        double niinf = c.bmax(XNRM);
        double mu = pow(niinf / nm, 0.25);
        if (!(mu > 0.125)) mu = 0.125;
        if (mu > 8.0) mu = 8.0;
        double mu2 = mu*mu, rmu = 1.0/mu, rmu2 = rmu*rmu;
        int nxt = cur ^ 1;
        {   // M' = 0.25*(mu^2 M + mu^-2 M^-1) + 0.5 I ; Y' = 0.5*(mu Y + G/mu)
            double r = 0.25 * (mu2 * mc[ij2] + rmu2 * iy[ij2]);
            if (c.diagre) r += 0.5;
            mo[ij2] = r;
            yo[ij2] = 0.5 * (mu * yc[ij2] + rmu * dG[ij2]);
            // fused row sums of M' -> bank[nxt]; zero bank[cur]
            double av = fabs(r);
            double dvv = fabs(r - (c.diagre ? 1.0 : 0.0));
            #pragma unroll
            for (int m = 32; m >= 1; m >>= 1){ av += __shfl_xor(av, m); dvv += __shfl_xor(dvv, m); }
            int w = c.t >> 6;
            if ((c.t & 63) == 0){ sh.redB[w] = dvv; sh.redB[16 + w] = av; }
            __syncthreads();
            int DEVn = nxt ? B_DEV1 : B_DEV0, INFn = nxt ? B_INF1 : B_INF0;
            int DEVc = cur ? B_DEV1 : B_DEV0, INFc = cur ? B_INF1 : B_INF0;
            int r0 = ((c.b & 127) << 1);
            if (c.t == 0){
                atomicAdd(&ws[DEVn + r0], sh.redB[0]+sh.redB[1]+sh.redB[2]+sh.redB[3]);
                atomicAdd(&ws[INFn + r0], sh.redB[16]+sh.redB[17]+sh.redB[18]+sh.redB[19]);
                if (c.b < 128){ ws[DEVc + r0] = 0.0; ws[INFc + r0] = 0.0; }
            }
            if (c.t == 256){
                atomicAdd(&ws[DEVn + r0+1], sh.redB[4]+sh.redB[5]+sh.redB[6]+sh.redB[7]);
                atomicAdd(&ws[INFn + r0+1], sh.redB[20]+sh.redB[21]+sh.redB[22]+sh.redB[23]);
                if (c.b < 128){ ws[DEVc + r0+1] = 0.0; ws[INFc + r0+1] = 0.0; }
            }
        }
        c.GS(nullptr);
        cur = nxt;
        dev = c.bmax(cur ? B_DEV1 : B_DEV0);
        nm  = c.bmax(cur ? B_INF1 : B_INF0);
        double* tm = mc; mc = mo; mo = tm;
        tm = yc; yc = yo; yo = tm;
    }
    EW[ij2] = yc[ij2];                                     // result -> S_EW
}

// ---- stage: one inverse-free Newton-Schulz sqrt pass: S_EW <- sqrt(S_EW) ----
// Fused dev row sums in the E-gemm epilogue (double-buffered banks).
__global__ __launch_bounds__(512, 1) void k_logm_sq(double* __restrict__ ws)
{
    __shared__ ShMemC sh;
    Ctx c; c.init(ws, &sh);
    double* dYy = c.SL(S_Y);  double* dY2 = c.SL(S_Y2);
    double* dX  = c.SL(S_X);  double* dX2 = c.SL(S_X2);
    double* dT  = c.SL(S_T);
    double* EW  = c.SL(S_EW);
    const int ij2 = c.ij2;

    c.partials(EW, NRM_ROW, NRM_COL, -1);
    if (c.t == 0){ ws[B_DEV0 + c.b] = 0.0; ws[B_DEV1 + c.b] = 0.0; }
    c.GS(nullptr);
    double cc = sqrt(c.bmax(NRM_COL) * c.bmax(NRM_ROW));
    double invc = 1.0 / cc, sc = sqrt(cc);
    dYy[ij2] = EW[ij2] * invc;                             // Y0 = B/c
    dX[ij2]  = c.diagre ? 1.0 : 0.0;                       // Z0 = I
    c.GS(nullptr);
    double* Ycur = dYy; double* Yalt = dY2;
    double* Zcur = dX;  double* Zalt = dX2;
    for (int it = 0; it < 30; it++){
        int wr = it & 1;
        double* devW = ws + (wr ? B_DEV1 : B_DEV0);
        double* devZ = ws + (wr ? B_DEV0 : B_DEV1);
        c.gemm(Zcur, Ycur, dT, 1,0, 1,0, 1.0, 0.0, nullptr, 0,0, 0.0, nullptr,
               devW, devZ);                                // E = Z Y (+dev rows)
        c.GS(nullptr);
        double dv = c.bmax(wr ? B_DEV1 : B_DEV0);
        if (dv < 1e-11) break;
        // team0: Y' = 0.5 Y (3I - E) ; team1: Z' = 0.5 (3I - E) Z  (independent)
        GOp oY = { Ycur, dT, Yalt, 1,0, -1.0,3.0, 0.5, 0.0, nullptr, 0,0, 0.0, nullptr };
        GOp oZ = { dT, Zcur, Zalt, -1.0,3.0, 1,0, 0.5, 0.0, nullptr, 0,0, 0.0, nullptr };
        c.gemm2(oY, oZ);
        c.GS(nullptr);
        double* tm = Ycur; Ycur = Yalt; Yalt = tm;
        tm = Zcur; Zcur = Zalt; Zalt = tm;
    }
    EW[ij2] = sc * Ycur[ij2];                              // result -> S_EW
}

// ---- stage: Cayley + adaptive artanh + S-build ----
__global__ __launch_bounds__(512, 1) void k_logm_cay(double* __restrict__ ws, int invBase)
{
    __shared__ ShMemC sh;
    Ctx c; c.init(ws, &sh);
    double* dX  = c.SL(S_X);
    double* dG  = c.SL(S_G);  double* dG2 = c.SL(S_G2);
    double* dW  = c.SL(S_W);  double* dV  = c.SL(S_V);
    double* dLT = c.SL(S_LAT);
    double* dS  = c.SL(PBASE);
    double* EW  = c.SL(S_EW);
    const int ij2 = c.ij2;

    // A = B + I ; seed X0 = 0.75I - 0.25B (resid = 0.25(I-B)^2, small)
    dG[ij2] = EW[ij2] + (c.diagre ? 1.0 : 0.0);
    dX[ij2] = -0.25 * EW[ij2] + (c.diagre ? 0.75 : 0.0);
    c.GS(nullptr);
    c.partials(dG, NRM_ROW, NRM_COL, -1);                  // norms for fallback
    c.GS(nullptr);
    double* giy = c.inv(dG, 0.0, 40, 2, invBase);
    c.gemm(EW, giy, dW, 1,-1, 1,0, 1.0, 0.0, nullptr, 0,0, 0.0, nullptr,
           nullptr, nullptr);                              // W=(B-I)(B+I)^-1
    c.GS(nullptr);
    c.gemm(dW, dW, dV, 1,0, 1,0, 1.0, 0.0, nullptr, 0,0, 0.0, nullptr,
           nullptr, nullptr);                              // V = W^2
    c.partials(dW, NRM_ROW, -1, -1);                       // ||W||inf (rows-only)
    c.GS(nullptr);
    double nW = c.bmax(NRM_ROW);
    double q = nW * nW;
    int J = 19;
    if (q < 0.5){
        J = 1;
        double qp = q * q;
        while (J < 19 && qp >= 1e-16 * (1.0 - q)){ qp *= q; J++; }
    }
    dG[ij2] = c.diagre ? 1.0/(double)(2*J + 1) : 0.0;      // Horner seed
    c.GS(nullptr);
    double* gc = dG; double* go = dG2;
    for (int j = J - 1; j >= 0; j--){
        c.gemm(dV, gc, go, 1,0, 1,0, 1.0, 0.0, nullptr, 0,0, 1.0/(double)(2*j + 1),
               nullptr, nullptr, nullptr);
        c.GS(nullptr);
        double* tm = gc; gc = go; go = tm;
    }
    c.gemm(dW, gc, dLT, 1,0, 1,0, 1.0, 0.0, nullptr, 0,0, 0.0, nullptr,
           nullptr, nullptr);                              // LAT = artanh(W)
    c.GS(nullptr);
    double vv = dLT[ij2] - dLT[c.tr_idx];
    dS[ij2] = c.pl ? -LOG_SCALE * vv : LOG_SCALE * vv;     // S = 32*conj(LAT-LAT^T)
}

// theta per u (rigorous upper bound); theta>4 -> scaling+squaring pool
__global__ __launch_bounds__(256) void k_theta_pool(double* ws)
{
    __shared__ double th[256]; __shared__ int rk[256];
    int t = threadIdx.x;
    double nS = ws[SC_NORMS2];
    double cr = ws[W_C_RE + t], ci = ws[W_C_IM + t];
    th[t] = sqrt(cr*cr + ci*ci) * nS;
    __syncthreads();
    int r = 0;
    for (int v = 0; v < 256; v++){
        if (th[v] > th[t] || (th[v] == th[t] && v < t)) r++;
    }
    rk[t] = r;
    __syncthreads();
    if (t == 0){
        int cnt = 0;
        for (int u = 0; u < 256; u++){
            double s = 0.0; int slot = -1;
            if (th[u] > 4.0 && rk[u] < NPOOL){
                double e = ceil(log2(th[u] / 4.0));
                if (e < 1.0) e = 1.0; if (e > 12.0) e = 12.0;
                s = e; slot = cnt;
                ws[W_SLOTU + cnt] = (double)u;
                cnt++;
            }
            ws[W_SU + u] = s;
            ws[W_SLOT + u] = (double)slot;
        }
        for (int k = cnt; k < NPOOL; k++) ws[W_SLOTU + k] = -1.0;
    }
}

// weights w[u][k] = (c_u / 2^{s_u})^k / k!
__global__ __launch_bounds__(256) void k_weights(double* ws)
{
    int u = threadIdx.x;
    double sc = ldexp(1.0, -(int)ws[W_SU + u]);
    double cr = ws[W_C_RE + u] * sc, ci = ws[W_C_IM + u] * sc;
    double wr = 1.0, wi = 0.0;
    ws[W_W + (u*33)*2] = 1.0; ws[W_W + (u*33)*2 + 1] = 0.0;
    for (int k = 1; k <= 32; k++){
        double inv = 1.0 / (double)k;
        double nr = (wr*cr - wi*ci) * inv, ni = (wr*ci + wi*cr) * inv;
        wr = nr; wi = ni;
        ws[W_W + (u*33 + k)*2] = wr;
        ws[W_W + (u*33 + k)*2 + 1] = wi;
    }
}

// exp_tens[u] = sum_k w[u][k] S^k -> f32 out (non-pooled) or fp64 pool base
__global__ __launch_bounds__(256) void k_combo(double* ws, float* out, long off_ex, int f,
                                               int pass, int K)
{
    __shared__ double wre[16][33], wim[16][33];
    __shared__ int anywork;
    int t = threadIdx.x;
    int row = blockIdx.x, ug = blockIdx.y;
    if (t == 0) anywork = (pass == 0) ? 1 : 0;
    __syncthreads();
    if (pass > 0 && t < 16){
        int u = ug*16 + t;
        int slot = (int)ws[W_SLOT + u];
        int phys = slot - pass * K;
        if (slot >= 0 && phys >= 0 && phys < K) anywork = 1;
    }
    __syncthreads();
    if (!anywork) return;
    for (int i = t; i < 16*33; i += 256){
        int g = i / 33, k = i % 33;
        int u = ug*16 + g;
        wre[g][k] = ws[W_W + (u*33 + k)*2];
        wim[g][k] = ws[W_W + (u*33 + k)*2 + 1];
    }
    __syncthreads();
    int j = t, ij = row*256 + j;
    double ar[16], ai[16];
    #pragma unroll
    for (int g = 0; g < 16; g++){
        ar[g] = (row == j) ? wre[g][0] : 0.0;
        ai[g] = (row == j) ? wim[g][0] : 0.0;
    }
    for (int k = 1; k <= 32; k++){
        const double* SP = ws + MAT0 + (size_t)(PBASE + k - 1) * MATD;
        double sre = SP[ij], sim = SP[NN + ij];
        #pragma unroll
        for (int g = 0; g < 16; g++){
            ar[g] += wre[g][k]*sre - wim[g][k]*sim;
            ai[g] += wre[g][k]*sim + wim[g][k]*sre;
        }
    }
    for (int g = 0; g < 16; g++){
        int u = ug*16 + g;
        int slot = (int)ws[W_SLOT + u];
        if (slot >= 0){
            int phys = slot - pass * K;
            if (phys >= 0 && phys < K){
                double* P = ws + MAT0 + (size_t)(POOL0 + phys) * MATD;
                P[ij] = ar[g]; P[NN + ij] = ai[g];
            }
        } else if (pass == 0){
            long base = off_ex + (long)u * NN * f + (long)ij * f;
            out[base] = (float)ar[g];
            if (f == 2) out[base + 1] = (float)ai[g];
        }
    }
}

// pool squaring
__global__ __launch_bounds__(256) void k_pool_sq(double* ws, int round, int pass, int K)
{
    int z = blockIdx.z;
    int vs = pass * K + z;
    int u = (vs < NPOOL) ? (int)ws[W_SLOTU + vs] : -1;
    if (u < 0) return;
    if (round > (int)ws[W_SU + u]) return;
    const double* A = ws + MAT0 + (size_t)(POOL0 + ((round & 1) ? 0 : K) + z) * MATD;
    double* C = ws + MAT0 + (size_t)(POOL0 + ((round & 1) ? K : 0) + z) * MATD;
    int tx = threadIdx.x & 15, ty = threadIdx.x >> 4;
    int row = blockIdx.y*16 + ty, col = blockIdx.x*16 + tx;
    __shared__ double Asr[16][17], Asi[16][17], Bsr[16][17], Bsi[16][17];
    double cr = 0.0, ci = 0.0;
    for (int k0 = 0; k0 < 256; k0 += 16){
        Asr[ty][tx] = A[row*256 + k0 + tx];
        Asi[ty][tx] = A[NN + row*256 + k0 + tx];
        Bsr[ty][tx] = A[(k0 + ty)*256 + col];
        Bsi[ty][tx] = A[NN + (k0 + ty)*256 + col];
        __syncthreads();
        #pragma unroll
        for (int kk = 0; kk < 16; kk++){
            double xr = Asr[ty][kk], xi = Asi[ty][kk];
            double yr = Bsr[kk][tx], yi = Bsi[kk][tx];
            cr += xr*yr - xi*yi;
            ci += xr*yi + xi*yr;
        }
        __syncthreads();
    }
    C[row*256 + col] = cr;
    C[NN + row*256 + col] = ci;
}

__global__ __launch_bounds__(256) void k_pool_out(const double* ws, float* out, long off_ex,
                                                  int f, int pass, int K)
{
    int z = blockIdx.y;
    int vs = pass * K + z;
    int u = (vs < NPOOL) ? (int)ws[W_SLOTU + vs] : -1;
    if (u < 0) return;
    int su = (int)ws[W_SU + u];
    int ij = blockIdx.x * 256 + threadIdx.x;
    const double* P = ws + MAT0 + (size_t)(POOL0 + ((su & 1) ? K : 0) + z) * MATD;
    long base = off_ex + (long)u * NN * f + (long)ij * f;
    out[base] = (float)P[ij];
    if (f == 2) out[base + 1] = (float)P[NN + ij];
}

__global__ __launch_bounds__(256) void k_cast_out(const double* ws, int slot, float* out, long off, int f)
{
    int ij = blockIdx.x * 256 + threadIdx.x;
    const double* P = ws + MAT0 + (size_t)slot * MATD;
    out[off + (long)ij * f] = (float)P[ij];
    if (f == 2) out[off + (long)ij * f + 1] = (float)P[NN + ij];
}

// ============================ host ============================
extern "C" void kernel_launch(void* const* d_in, const int* in_sizes, int n_in,
                              void* d_out, int out_size, void* d_ws, size_t ws_size,
                              hipStream_t stream)
{
    double* ws = (double*)d_ws;
    float* out = (float*)d_out;

    int f = (out_size >= 33816832) ? 2 : 1;
    long off_ex = 256;
    long off_uw = off_ex + (long)f * 16777216L;
    long off_ew = off_uw + (long)f * 65536L;

    k_init<<<128, 256, 0, stream>>>(ws);
    k_detect<<<1, 64, 0, stream>>>(d_in[0], ws);
    k_small<<<1, 256, 0, stream>>>(d_in[0], d_in[1], d_in[2], d_in[3], d_in[4], ws, out);

    long slotsAvail = (long)(ws_size / 8 - MAT0) / MATD;
    if (slotsAvail < POOL0 + 32) return;
    int K = (int)((slotsAvail - POOL0) / 2);
    if (K > NPOOL) K = NPOOL;
    if (K < 16) K = 16;
    int P = (NPOOL + K - 1) / K;

    auto MP = [&](int s){ return ws + MAT0 + (size_t)s * MATD; };
    auto ZG = [&](int a, int b, int c, int preA, int preB, double al, double be,
                  int d, double ga, int fm, int round){
        k_zgemm<<<dim3(16,16,1), 256, 0, stream>>>(MP(a), MP(b), MP(c),
            d >= 0 ? MP(d) : nullptr, preA, preB, al, be, ga, ws,
            fm, round, 0, 0, 0L, 0L, 0L);
    };
    auto GEMM = [&](int a, int b, int c, int preA, int preB, double al, double be, int d, double ga){
        ZG(a, b, c, preA, preB, al, be, d, ga, 0, 0);
    };

    k_build_mats<<<256, 256, 0, stream>>>(d_in[5], d_in[6], d_in[7], d_in[8], ws);
    k_cast_out<<<256, 256, 0, stream>>>(ws, S_NUW, out, off_uw, f);

    // -------- expm(new_uw): scaling + Paterson-Stockmeyer deg-16 Taylor + squarings ----
    static const double INVF[17] = {
        1.0, 1.0, 0.5, 1.0/6.0, 1.0/24.0, 1.0/120.0, 1.0/720.0, 1.0/5040.0,
        1.0/40320.0, 1.0/362880.0, 1.0/3628800.0, 1.0/39916800.0, 1.0/479001600.0,
        1.0/6227020800.0, 1.0/87178291200.0, 1.0/1307674368000.0, 1.0/20922789888000.0 };
    k_norm1inf<<<1, 256, 0, stream>>>(MP(S_NUW), ws, 8);
    k_expm_prep<<<1, 64, 0, stream>>>(ws);
    k_combine<<<256, 256, 0, stream>>>(ws, S_LAT, S_NUW, -1, -1, -1, 1.0, 0, 0, 0, 0.0, 1);
    GEMM(S_LAT, S_LAT, S_T2, 0, 0, 1.0, 0.0, -1, 0.0);
    GEMM(S_T2, S_LAT, S_T3, 0, 0, 1.0, 0.0, -1, 0.0);
    GEMM(S_T2, S_T2, S_T4, 0, 0, 1.0, 0.0, -1, 0.0);
    k_combine<<<256, 256, 0, stream>>>(ws, S_E1, -1, -1, -1, -1, 0, 0, 0, 0, INVF[16], 0);
    for (int b = 3; b >= 0; b--){
        GEMM(S_T4, S_E1, S_E2, 0, 0, 1.0, 0.0, -1, 0.0);
        k_combine<<<256, 256, 0, stream>>>(ws, S_E1, S_E2, S_LAT, S_T2, S_T3,
            1.0, INVF[4*b+1], INVF[4*b+2], INVF[4*b+3], INVF[4*b], 0);
    }
    for (int r = 1; r <= 10; r++){
        int src = (r & 1) ? S_E1 : S_E2, dst = (r & 1) ? S_E2 : S_E1;
        ZG(src, src, dst, 0, 0, 1.0, 0.0, -1, 0.0, 1, r);
    }
    GEMM(S_EW, S_E1, S_M2, 1, 0, 1.0, 0.0, -1, 0.0);   // new_Ew = conj(Ew) expm(new_uw)
    k_cast_out<<<256, 256, 0, stream>>>(ws, S_M2, out, off_ew, f);

    // -------- logm(Ew): 5 cooperative stage launches (rocprof per-stage rows) ----
    {
        int ib0 = 0, ib1 = 20, ib2 = 40;
        { void* a[] = { (void*)&ws, (void*)&ib0 };
          hipLaunchCooperativeKernel((void*)k_logm_db, dim3(256), dim3(512), a, 0, stream); }
        { void* a[] = { (void*)&ws, (void*)&ib1 };
          hipLaunchCooperativeKernel((void*)k_logm_db, dim3(256), dim3(512), a, 0, stream); }
        { void* a[] = { (void*)&ws };
          hipLaunchCooperativeKernel((void*)k_logm_sq, dim3(256), dim3(512), a, 0, stream); }
        { void* a[] = { (void*)&ws };
          hipLaunchCooperativeKernel((void*)k_logm_sq, dim3(256), dim3(512), a, 0, stream); }
        { void* a[] = { (void*)&ws, (void*)&ib2 };
          hipLaunchCooperativeKernel((void*)k_logm_cay, dim3(256), dim3(512), a, 0, stream); }
    }

    // -------- batched exp_tens = expm(c_u S): shared powers + pooled squaring --------
    k_norm1inf<<<1, 256, 0, stream>>>(MP(PBASE), ws, 12);
    k_fro<<<1, 256, 0, stream>>>(MP(PBASE), ws);
    k_snorm<<<1, 1, 0, stream>>>(ws);
    k_theta_pool<<<1, 256, 0, stream>>>(ws);
    k_weights<<<1, 256, 0, stream>>>(ws);
    for (int m = 1; m < 32; m *= 2){
        int cnt = (m < 32 - m) ? m : (32 - m);
        k_zgemm<<<dim3(16,16,cnt), 256, 0, stream>>>(MP(PBASE + m - 1), MP(PBASE), MP(PBASE + m),
            nullptr, 0, 0, 1.0, 0.0, 0.0, ws, 0, 0, 0, 0, 0L, MATD, MATD);
    }
    for (int p = 0; p < P; p++){
        k_combo<<<dim3(256,16), 256, 0, stream>>>(ws, out, off_ex, f, p, K);
        for (int r = 1; r <= 12; r++)
            k_pool_sq<<<dim3(16,16,K), 256, 0, stream>>>(ws, r, p, K);
        k_pool_out<<<dim3(256,K), 256, 0, stream>>>(ws, out, off_ex, f, p, K);
    }
}